// Round 4
// baseline (2179.151 us; speedup 1.0000x reference)
//
#include <hip/hip_runtime.h>
#include <math.h>

#define NN 50000
#define EE 400000
#define RR 3
#define NH 3
#define FIN 128
#define HID 64
#define FOUT 64
#define NC 16
#define NB 8

// ======== degree histogram (int atomics, low contention) ========
__global__ void k_deg(const int* __restrict__ src, const int* __restrict__ dst,
                      int* __restrict__ degs, int* __restrict__ degd) {
  int i = blockIdx.x * 256 + threadIdx.x;
  if (i >= RR * EE) return;
  int r = i / EE;
  atomicAdd(&degs[r * NN + src[i]], 1);
  atomicAdd(&degd[r * NN + dst[i]], 1);
}

__global__ void k_norm(const int* __restrict__ degs, const int* __restrict__ degd,
                       float* __restrict__ ns, float* __restrict__ nd) {
  int i = blockIdx.x * 256 + threadIdx.x;
  if (i >= RR * NN) return;
  ns[i] = 1.0f / sqrtf((float)(degs[i] > 1 ? degs[i] : 1));
  nd[i] = 1.0f / sqrtf((float)(degd[i] > 1 ? degd[i] : 1));
}

// ======== exclusive scan over degd (RR*NN) -> offs, 3 kernels ========
__global__ void k_scan1(const int* __restrict__ deg, int* __restrict__ offs,
                        int* __restrict__ bsum) {
  __shared__ int sh[256];
  int gid = blockIdx.x * 256 + threadIdx.x;
  int v = (gid < RR * NN) ? deg[gid] : 0;
  sh[threadIdx.x] = v;
  __syncthreads();
  for (int off = 1; off < 256; off <<= 1) {
    int t = (threadIdx.x >= off) ? sh[threadIdx.x - off] : 0;
    __syncthreads();
    sh[threadIdx.x] += t;
    __syncthreads();
  }
  if (gid < RR * NN) offs[gid] = sh[threadIdx.x] - v;
  if (threadIdx.x == 255) bsum[blockIdx.x] = sh[255];
}

__global__ void k_scan2(int* __restrict__ bsum, int nb) {
  __shared__ int sh[1024];
  int v = (threadIdx.x < nb) ? bsum[threadIdx.x] : 0;
  sh[threadIdx.x] = v;
  __syncthreads();
  for (int off = 1; off < 1024; off <<= 1) {
    int t = (threadIdx.x >= off) ? sh[threadIdx.x - off] : 0;
    __syncthreads();
    sh[threadIdx.x] += t;
    __syncthreads();
  }
  if (threadIdx.x < nb) bsum[threadIdx.x] = sh[threadIdx.x] - v;
}

__global__ void k_scan3(int* __restrict__ offs, const int* __restrict__ bsum,
                        int* __restrict__ cursor) {
  int i = blockIdx.x * 256 + threadIdx.x;
  if (i >= RR * NN) return;
  int v = offs[i] + bsum[i / 256];
  offs[i] = v;
  cursor[i] = v;
}

__global__ void k_fill(const int* __restrict__ src, const int* __restrict__ dst,
                       int* __restrict__ cursor, int* __restrict__ esrc) {
  int i = blockIdx.x * 256 + threadIdx.x;
  if (i >= RR * EE) return;
  int r = i / EE;
  int d = dst[i];
  int pos = atomicAdd(&cursor[r * NN + d], 1);
  esrc[pos] = src[i];
}

// ======== conv1 matmul, LDS-staged W, 8-node register blocking ========
// hw[(r*NN+n)*HID+k] = ns[r][n] * sum_t x[n][t]*W1[r][t][k]
__global__ __launch_bounds__(256) void k_mm1v(const float* __restrict__ x,
                                              const float* __restrict__ W1,
                                              const float* __restrict__ ns,
                                              float* __restrict__ hw) {
  __shared__ __align__(16) float ws[FIN * HID];  // 32 KB
  int r = blockIdx.y;
  {
    const float4* wsrc = (const float4*)(W1 + (size_t)r * FIN * HID);
    float4* wdst = (float4*)ws;
#pragma unroll
    for (int i = 0; i < 8; ++i) wdst[threadIdx.x + i * 256] = wsrc[threadIdx.x + i * 256];
  }
  __syncthreads();
  int lane = threadIdx.x & 63, wv = threadIdx.x >> 6;
  const int TIL = (NN + 31) / 32;
  for (int tile = blockIdx.x; tile < TIL; tile += gridDim.x) {
    int nb = tile * 32 + wv * 8;
    float acc[8] = {0.f, 0.f, 0.f, 0.f, 0.f, 0.f, 0.f, 0.f};
    for (int t = 0; t < FIN; t += 4) {
      float4 xv[8];
#pragma unroll
      for (int j = 0; j < 8; ++j) {
        int n = nb + j;
        n = n < NN ? n : NN - 1;
        xv[j] = *(const float4*)(x + (size_t)n * FIN + t);
      }
      float w0 = ws[t * HID + lane];
      float w1 = ws[(t + 1) * HID + lane];
      float w2 = ws[(t + 2) * HID + lane];
      float w3 = ws[(t + 3) * HID + lane];
#pragma unroll
      for (int j = 0; j < 8; ++j)
        acc[j] += xv[j].x * w0 + xv[j].y * w1 + xv[j].z * w2 + xv[j].w * w3;
    }
#pragma unroll
    for (int j = 0; j < 8; ++j) {
      int n = nb + j;
      if (n < NN) hw[((size_t)r * NN + n) * HID + lane] = acc[j] * ns[r * NN + n];
    }
  }
}

// ======== conv1 gather + bias + L2 normalize (one wave per node) ========
__global__ void k_g1(const int* __restrict__ offs, const int* __restrict__ degd,
                     const int* __restrict__ esrc, const float* __restrict__ hw,
                     const float* __restrict__ nd, const float* __restrict__ b1,
                     float* __restrict__ h1) {
  int node = blockIdx.x * 4 + (threadIdx.x >> 6);
  int lane = threadIdx.x & 63;
  if (node >= NN) return;
  float v = 0.f;
#pragma unroll
  for (int r = 0; r < RR; ++r) {
    int start = offs[r * NN + node];
    int deg = degd[r * NN + node];
    float t = 0.f;
    for (int j = 0; j < deg; ++j) {
      int s = esrc[start + j];
      t += hw[((size_t)r * NN + s) * HID + lane];
    }
    v += t * nd[r * NN + node];
  }
  v += b1[lane] + b1[HID + lane] + b1[2 * HID + lane];
  float sq = v * v;
  for (int off = 32; off; off >>= 1) sq += __shfl_xor(sq, off);
  float nrm = sqrtf(sq);
  nrm = nrm > 1e-12f ? nrm : 1e-12f;
  h1[node * HID + lane] = v / nrm;
}

// ======== GAT matmul + fused el/er, LDS-staged W (48 KB), block=192 ========
// f[n][col] = sum_t h1[n][t]*Wg[r][t][col]; el/er = wave-reduced dot with al/ar
__global__ __launch_bounds__(192) void k_mmgv(const float* __restrict__ h1,
                                              const float* __restrict__ Wg,
                                              const float* __restrict__ al,
                                              const float* __restrict__ ar,
                                              float* __restrict__ f,
                                              float* __restrict__ el,
                                              float* __restrict__ er, int r) {
  __shared__ __align__(16) float ws[HID * NH * HID];  // 48 KB
  {
    const float4* wsrc = (const float4*)(Wg + (size_t)r * HID * NH * HID);
    float4* wdst = (float4*)ws;
#pragma unroll
    for (int i = 0; i < 16; ++i) wdst[threadIdx.x + i * 192] = wsrc[threadIdx.x + i * 192];
  }
  int col = threadIdx.x;
  int h = col >> 6;
  float alv = al[r * (NH * HID) + col];
  float arv = ar[r * (NH * HID) + col];
  __syncthreads();
  const int TIL = NN / 8;  // 6250 exact
  for (int tile = blockIdx.x; tile < TIL; tile += gridDim.x) {
    int nb = tile * 8;
    float acc[8] = {0.f, 0.f, 0.f, 0.f, 0.f, 0.f, 0.f, 0.f};
    for (int t = 0; t < HID; t += 4) {
      float4 xv[8];
#pragma unroll
      for (int j = 0; j < 8; ++j)
        xv[j] = *(const float4*)(h1 + (size_t)(nb + j) * HID + t);
      float w0 = ws[t * (NH * HID) + col];
      float w1 = ws[(t + 1) * (NH * HID) + col];
      float w2 = ws[(t + 2) * (NH * HID) + col];
      float w3 = ws[(t + 3) * (NH * HID) + col];
#pragma unroll
      for (int j = 0; j < 8; ++j)
        acc[j] += xv[j].x * w0 + xv[j].y * w1 + xv[j].z * w2 + xv[j].w * w3;
    }
#pragma unroll
    for (int j = 0; j < 8; ++j) {
      int n = nb + j;
      f[(size_t)n * (NH * HID) + col] = acc[j];
      float pe = acc[j] * alv, pr = acc[j] * arv;
#pragma unroll
      for (int off = 32; off; off >>= 1) {
        pe += __shfl_xor(pe, off);
        pr += __shfl_xor(pr, off);
      }
      if ((col & 63) == 0) {
        el[n * NH + h] = pe;
        er[n * NH + h] = pr;
      }
    }
  }
}

// ======== GAT gather: softmax over in-edges + weighted feature sum ========
__global__ void k_gatg(const int* __restrict__ offs, const int* __restrict__ degd,
                       const int* __restrict__ esrc, const float* __restrict__ f,
                       const float* __restrict__ el, const float* __restrict__ er,
                       float* __restrict__ gat, int r, int accf) {
  int node = blockIdx.x * 4 + (threadIdx.x >> 6);
  int lane = threadIdx.x & 63;
  if (node >= NN) return;
  int start = offs[r * NN + node];
  int deg = degd[r * NN + node];
  float erv[NH], m[NH];
#pragma unroll
  for (int h = 0; h < NH; ++h) {
    erv[h] = er[node * NH + h];
    m[h] = -1e30f;
  }
  for (int j = 0; j < deg; ++j) {
    int s = esrc[start + j];
#pragma unroll
    for (int h = 0; h < NH; ++h) {
      float ev = el[s * NH + h] + erv[h];
      ev = ev > 0.f ? ev : 0.2f * ev;
      m[h] = fmaxf(m[h], ev);
    }
  }
  float z[NH] = {0.f, 0.f, 0.f};
  float acc[NH] = {0.f, 0.f, 0.f};
  for (int j = 0; j < deg; ++j) {
    int s = esrc[start + j];
#pragma unroll
    for (int h = 0; h < NH; ++h) {
      float ev = el[s * NH + h] + erv[h];
      ev = ev > 0.f ? ev : 0.2f * ev;
      float w = __expf(ev - m[h]);
      z[h] += w;
      acc[h] += w * f[(size_t)s * (NH * HID) + h * HID + lane];
    }
  }
#pragma unroll
  for (int h = 0; h < NH; ++h) {
    float outv = acc[h] / (z[h] + 1e-9f);
    size_t idx = (size_t)node * (NH * HID) + h * HID + lane;
    gat[idx] = (accf ? gat[idx] : 0.f) + outv;
  }
}

__global__ void k_relubg(float* __restrict__ gat, const float* __restrict__ bg) {
  int i = blockIdx.x * 256 + threadIdx.x;
  if (i >= NN * NH * HID) return;
  int j = i % (NH * HID);
  float v = gat[i] + bg[j] + bg[NH * HID + j] + bg[2 * NH * HID + j];
  gat[i] = v > 0.f ? v : 0.f;
}

// ======== conv2 matmul, rows = NN*NH, LDS-staged W2 (16 KB) ========
// hw[row*FOUT+o] = ns[r][row/NH] * sum_t gat[row*HID+t]*W2[r][t][o]
__global__ __launch_bounds__(256) void k_mm2v(const float* __restrict__ g,
                                              const float* __restrict__ W2,
                                              const float* __restrict__ ns,
                                              float* __restrict__ hw, int r) {
  __shared__ __align__(16) float ws[HID * FOUT];  // 16 KB
  {
    const float4* wsrc = (const float4*)(W2 + (size_t)r * HID * FOUT);
    float4* wdst = (float4*)ws;
#pragma unroll
    for (int i = 0; i < 4; ++i) wdst[threadIdx.x + i * 256] = wsrc[threadIdx.x + i * 256];
  }
  __syncthreads();
  int lane = threadIdx.x & 63, wv = threadIdx.x >> 6;
  const int ROWS = NN * NH;
  const int TIL = (ROWS + 31) / 32;
  for (int tile = blockIdx.x; tile < TIL; tile += gridDim.x) {
    int rb = tile * 32 + wv * 8;
    float acc[8] = {0.f, 0.f, 0.f, 0.f, 0.f, 0.f, 0.f, 0.f};
    for (int t = 0; t < HID; t += 4) {
      float4 xv[8];
#pragma unroll
      for (int j = 0; j < 8; ++j) {
        int row = rb + j;
        row = row < ROWS ? row : ROWS - 1;
        xv[j] = *(const float4*)(g + (size_t)row * HID + t);
      }
      float w0 = ws[t * FOUT + lane];
      float w1 = ws[(t + 1) * FOUT + lane];
      float w2 = ws[(t + 2) * FOUT + lane];
      float w3 = ws[(t + 3) * FOUT + lane];
#pragma unroll
      for (int j = 0; j < 8; ++j)
        acc[j] += xv[j].x * w0 + xv[j].y * w1 + xv[j].z * w2 + xv[j].w * w3;
    }
#pragma unroll
    for (int j = 0; j < 8; ++j) {
      int row = rb + j;
      if (row < ROWS) {
        int n = row / NH;
        hw[(size_t)row * FOUT + lane] = acc[j] * ns[r * NN + n];
      }
    }
  }
}

// ======== conv2 gather ========
__global__ void k_g2(const int* __restrict__ offs, const int* __restrict__ degd,
                     const int* __restrict__ esrc, const float* __restrict__ hw,
                     const float* __restrict__ nd, float* __restrict__ agg2,
                     int r, int accf) {
  int node = blockIdx.x * 4 + (threadIdx.x >> 6);
  int lane = threadIdx.x & 63;
  if (node >= NN) return;
  int start = offs[r * NN + node];
  int deg = degd[r * NN + node];
  float acc[NH] = {0.f, 0.f, 0.f};
  for (int j = 0; j < deg; ++j) {
    int s = esrc[start + j];
#pragma unroll
    for (int h = 0; h < NH; ++h)
      acc[h] += hw[(size_t)s * (NH * FOUT) + h * FOUT + lane];
  }
  float ndv = nd[r * NN + node];
#pragma unroll
  for (int h = 0; h < NH; ++h) {
    size_t idx = (size_t)node * (NH * FOUT) + h * FOUT + lane;
    agg2[idx] = (accf ? agg2[idx] : 0.f) + acc[h] * ndv;
  }
}

__global__ void k_sig(float* __restrict__ agg2, const float* __restrict__ b2) {
  int i = blockIdx.x * 256 + threadIdx.x;
  if (i >= NN * NH * FOUT) return;
  int o = i & (FOUT - 1);
  float v = agg2[i] + b2[o] + b2[FOUT + o] + b2[2 * FOUT + o];
  agg2[i] = 1.0f / (1.0f + __expf(-v));
}

__global__ void k_cnt2(const int* __restrict__ gid, float* __restrict__ cnt) {
  __shared__ int loc[NB];
  if (threadIdx.x < NB) loc[threadIdx.x] = 0;
  __syncthreads();
  int i = blockIdx.x * 256 + threadIdx.x;
  if (i < NN) atomicAdd(&loc[gid[i]], 1);
  __syncthreads();
  if (threadIdx.x < NB) atomicAdd(&cnt[threadIdx.x], (float)loc[threadIdx.x]);
}

__global__ void k_pool(const float* __restrict__ h3, const int* __restrict__ gid,
                       float* __restrict__ pooled) {
  int j = threadIdx.x;  // 0..191
  int start = blockIdx.x * 128;
  if (start >= NN) return;
  int end = start + 128;
  if (end > NN) end = NN;
  int gcur = gid[start];
  float acc = 0.f;
  for (int n = start; n < end; ++n) {
    int g = gid[n];
    if (g != gcur) {
      atomicAdd(&pooled[gcur * (NH * FOUT) + j], acc);
      acc = 0.f;
      gcur = g;
    }
    acc += h3[(size_t)n * (NH * FOUT) + j];
  }
  atomicAdd(&pooled[gcur * (NH * FOUT) + j], acc);
}

__global__ void k_final(const float* __restrict__ pooled, const float* __restrict__ cnt,
                        const float* __restrict__ Wc, const float* __restrict__ bc,
                        float* __restrict__ out) {
  int t = threadIdx.x;
  if (t >= NB * NH) return;
  int b = t / NH;
  float inv = 1.0f / fmaxf(cnt[b], 1.0f);
  const float* p = pooled + t * FOUT;
  float sacc = 0.f;
  for (int c = 0; c < NC; ++c) {
    float acc = bc[c];
    for (int o = 0; o < FOUT; ++o) acc += p[o] * inv * Wc[o * NC + c];
    sacc += 1.0f / (1.0f + __expf(-acc));
  }
  out[t] = sacc * (1.0f / NC);
}

extern "C" void kernel_launch(void* const* d_in, const int* in_sizes, int n_in,
                              void* d_out, int out_size, void* d_ws, size_t ws_size,
                              hipStream_t stream) {
  const float* x = (const float*)d_in[0];
  const int* src = (const int*)d_in[1];
  const int* dst = (const int*)d_in[2];
  const int* gid = (const int*)d_in[3];
  const float* W1 = (const float*)d_in[4];
  const float* b1 = (const float*)d_in[5];
  const float* Wg = (const float*)d_in[6];
  const float* al = (const float*)d_in[7];
  const float* ar = (const float*)d_in[8];
  const float* bg = (const float*)d_in[9];
  const float* W2 = (const float*)d_in[10];
  const float* b2 = (const float*)d_in[11];
  const float* Wc = (const float*)d_in[12];
  const float* bc = (const float*)d_in[13];
  float* out = (float*)d_out;

  // ---- workspace layout ----
  int* degs = (int*)d_ws;                        // RR*NN
  int* degd = degs + RR * NN;                    // RR*NN
  float* cnt = (float*)(degd + RR * NN);         // NB
  float* pooled = cnt + NB;                      // NB*NH*FOUT
  size_t zero_bytes = ((size_t)2 * RR * NN + NB + NB * NH * FOUT) * 4;
  int* offs = (int*)(pooled + NB * NH * FOUT);   // RR*NN (+1 pad)
  int* cursor = offs + RR * NN + 1;              // RR*NN
  int* bsum = cursor + RR * NN;                  // 1024
  int* esrc = bsum + 1024;                       // RR*EE
  float* ns = (float*)(esrc + (size_t)RR * EE);  // RR*NN
  float* nd = ns + RR * NN;                      // RR*NN
  float* el = nd + RR * NN;                      // NN*NH
  float* er = el + NN * NH;                      // NN*NH
  float* h1 = er + NN * NH;                      // NN*HID
  float* gat = h1 + (size_t)NN * HID;            // NN*NH*HID
  float* agg2 = gat + (size_t)NN * NH * HID;     // NN*NH*FOUT
  float* A = agg2 + (size_t)NN * NH * FOUT;      // RR*NN*HID == NN*192 staging

  hipMemsetAsync(d_ws, 0, zero_bytes, stream);

  const int nscan = RR * NN;
  const int nblk1 = (nscan + 255) / 256;

  // degrees + norms + CSR build
  k_deg<<<(RR * EE + 255) / 256, 256, 0, stream>>>(src, dst, degs, degd);
  k_norm<<<(nscan + 255) / 256, 256, 0, stream>>>(degs, degd, ns, nd);
  k_scan1<<<nblk1, 256, 0, stream>>>(degd, offs, bsum);
  k_scan2<<<1, 1024, 0, stream>>>(bsum, nblk1);
  k_scan3<<<nblk1, 256, 0, stream>>>(offs, bsum, cursor);
  k_fill<<<(RR * EE + 255) / 256, 256, 0, stream>>>(src, dst, cursor, esrc);

  // conv1: LDS-staged matmul (all relations in one launch) + gather+norm
  k_mm1v<<<dim3(256, RR), 256, 0, stream>>>(x, W1, ns, A);
  k_g1<<<(NN + 3) / 4, 256, 0, stream>>>(offs, degd, esrc, A, nd, b1, h1);

  // GAT per relation: matmul+el/er fused, then gather softmax
  for (int r = 0; r < RR; ++r) {
    k_mmgv<<<768, 192, 0, stream>>>(h1, Wg, al, ar, A, el, er, r);
    k_gatg<<<(NN + 3) / 4, 256, 0, stream>>>(offs, degd, esrc, A, el, er, gat, r, r != 0);
  }
  k_relubg<<<(NN * NH * HID + 255) / 256, 256, 0, stream>>>(gat, bg);

  // conv2 per relation
  for (int r = 0; r < RR; ++r) {
    k_mm2v<<<768, 256, 0, stream>>>(gat, W2, ns, A, r);
    k_g2<<<(NN + 3) / 4, 256, 0, stream>>>(offs, degd, esrc, A, nd, agg2, r, r != 0);
  }
  k_sig<<<(NN * NH * FOUT + 255) / 256, 256, 0, stream>>>(agg2, b2);

  // pooling + classifier
  k_cnt2<<<(NN + 255) / 256, 256, 0, stream>>>(gid, cnt);
  k_pool<<<(NN + 127) / 128, 192, 0, stream>>>(agg2, gid, pooled);
  k_final<<<1, 64, 0, stream>>>(pooled, cnt, Wc, bc, out);
}

// Round 5
// 1513.999 us; speedup vs baseline: 1.4393x; 1.4393x over previous
//
#include <hip/hip_runtime.h>
#include <math.h>

#define NN 50000
#define EE 400000
#define RR 3
#define NH 3
#define FIN 128
#define HID 64
#define FOUT 64
#define NC 16
#define NB 8

// ======== degree histogram (int atomics, low contention) ========
__global__ void k_deg(const int* __restrict__ src, const int* __restrict__ dst,
                      int* __restrict__ degs, int* __restrict__ degd) {
  int i = blockIdx.x * 256 + threadIdx.x;
  if (i >= RR * EE) return;
  int r = i / EE;
  atomicAdd(&degs[r * NN + src[i]], 1);
  atomicAdd(&degd[r * NN + dst[i]], 1);
}

__global__ void k_norm(const int* __restrict__ degs, const int* __restrict__ degd,
                       float* __restrict__ ns, float* __restrict__ nd) {
  int i = blockIdx.x * 256 + threadIdx.x;
  if (i >= RR * NN) return;
  ns[i] = 1.0f / sqrtf((float)(degs[i] > 1 ? degs[i] : 1));
  nd[i] = 1.0f / sqrtf((float)(degd[i] > 1 ? degd[i] : 1));
}

// ======== exclusive scan over degd (RR*NN) -> offs ========
__global__ void k_scan1(const int* __restrict__ deg, int* __restrict__ offs,
                        int* __restrict__ bsum) {
  __shared__ int sh[256];
  int gid = blockIdx.x * 256 + threadIdx.x;
  int v = (gid < RR * NN) ? deg[gid] : 0;
  sh[threadIdx.x] = v;
  __syncthreads();
  for (int off = 1; off < 256; off <<= 1) {
    int t = (threadIdx.x >= off) ? sh[threadIdx.x - off] : 0;
    __syncthreads();
    sh[threadIdx.x] += t;
    __syncthreads();
  }
  if (gid < RR * NN) offs[gid] = sh[threadIdx.x] - v;
  if (threadIdx.x == 255) bsum[blockIdx.x] = sh[255];
}

__global__ void k_scan2(int* __restrict__ bsum, int nb) {
  __shared__ int sh[1024];
  int v = (threadIdx.x < nb) ? bsum[threadIdx.x] : 0;
  sh[threadIdx.x] = v;
  __syncthreads();
  for (int off = 1; off < 1024; off <<= 1) {
    int t = (threadIdx.x >= off) ? sh[threadIdx.x - off] : 0;
    __syncthreads();
    sh[threadIdx.x] += t;
    __syncthreads();
  }
  if (threadIdx.x < nb) bsum[threadIdx.x] = sh[threadIdx.x] - v;
}

__global__ void k_scan3(int* __restrict__ offs, const int* __restrict__ bsum,
                        int* __restrict__ cursor) {
  int i = blockIdx.x * 256 + threadIdx.x;
  if (i >= RR * NN) return;
  int v = offs[i] + bsum[i / 256];
  offs[i] = v;
  cursor[i] = v;
}

__global__ void k_fill(const int* __restrict__ src, const int* __restrict__ dst,
                       int* __restrict__ cursor, int* __restrict__ esrc) {
  int i = blockIdx.x * 256 + threadIdx.x;
  if (i >= RR * EE) return;
  int r = i / EE;
  int d = dst[i];
  int pos = atomicAdd(&cursor[r * NN + d], 1);
  esrc[pos] = src[i];
}

// ======== conv1 matmul, LDS W, 4 rows/wave, VGPR-capped ========
__global__ __launch_bounds__(256, 4) void k_mm1v(const float* __restrict__ x,
                                                 const float* __restrict__ W1,
                                                 const float* __restrict__ ns,
                                                 float* __restrict__ hw) {
  __shared__ __align__(16) float ws[FIN * HID];  // 32 KB
  int r = blockIdx.y;
  {
    const float4* wsrc = (const float4*)(W1 + (size_t)r * FIN * HID);
    float4* wdst = (float4*)ws;
#pragma unroll
    for (int i = 0; i < 8; ++i) wdst[threadIdx.x + i * 256] = wsrc[threadIdx.x + i * 256];
  }
  __syncthreads();
  int lane = threadIdx.x & 63, wv = threadIdx.x >> 6;
  const int TIL = NN / 16;  // 3125 exact, 16 rows per block-tile (4 waves x 4 rows)
  for (int tile = blockIdx.x; tile < TIL; tile += gridDim.x) {
    int nb = tile * 16 + wv * 4;
    float acc[4] = {0.f, 0.f, 0.f, 0.f};
#pragma unroll 2
    for (int t = 0; t < FIN; t += 4) {
      float w0 = ws[t * HID + lane];
      float w1 = ws[(t + 1) * HID + lane];
      float w2 = ws[(t + 2) * HID + lane];
      float w3 = ws[(t + 3) * HID + lane];
#pragma unroll
      for (int j = 0; j < 4; ++j) {
        float4 xv = *(const float4*)(x + (size_t)(nb + j) * FIN + t);
        acc[j] += xv.x * w0 + xv.y * w1 + xv.z * w2 + xv.w * w3;
      }
    }
#pragma unroll
    for (int j = 0; j < 4; ++j) {
      int n = nb + j;
      hw[((size_t)r * NN + n) * HID + lane] = acc[j] * ns[r * NN + n];
    }
  }
}

// ======== conv1 gather + bias + L2 normalize (one wave per node) ========
__global__ void k_g1(const int* __restrict__ offs, const int* __restrict__ degd,
                     const int* __restrict__ esrc, const float* __restrict__ hw,
                     const float* __restrict__ nd, const float* __restrict__ b1,
                     float* __restrict__ h1) {
  int node = blockIdx.x * 4 + (threadIdx.x >> 6);
  int lane = threadIdx.x & 63;
  if (node >= NN) return;
  float v = 0.f;
#pragma unroll
  for (int r = 0; r < RR; ++r) {
    int start = offs[r * NN + node];
    int deg = degd[r * NN + node];
    float t = 0.f;
    for (int j = 0; j < deg; ++j) {
      int s = esrc[start + j];
      t += hw[((size_t)r * NN + s) * HID + lane];
    }
    v += t * nd[r * NN + node];
  }
  v += b1[lane] + b1[HID + lane] + b1[2 * HID + lane];
  float sq = v * v;
  for (int off = 32; off; off >>= 1) sq += __shfl_xor(sq, off);
  float nrm = sqrtf(sq);
  nrm = nrm > 1e-12f ? nrm : 1e-12f;
  h1[node * HID + lane] = v / nrm;
}

// ======== GAT matmul + fused el/er, LDS W (48 KB), 4 rows/iter ========
__global__ __launch_bounds__(192, 4) void k_mmgv(const float* __restrict__ h1,
                                                 const float* __restrict__ Wg,
                                                 const float* __restrict__ al,
                                                 const float* __restrict__ ar,
                                                 float* __restrict__ f,
                                                 float* __restrict__ el,
                                                 float* __restrict__ er, int r) {
  __shared__ __align__(16) float ws[HID * NH * HID];  // 48 KB
  {
    const float4* wsrc = (const float4*)(Wg + (size_t)r * HID * NH * HID);
    float4* wdst = (float4*)ws;
#pragma unroll
    for (int i = 0; i < 16; ++i) wdst[threadIdx.x + i * 192] = wsrc[threadIdx.x + i * 192];
  }
  int col = threadIdx.x;
  int h = col >> 6;
  float alv = al[r * (NH * HID) + col];
  float arv = ar[r * (NH * HID) + col];
  __syncthreads();
  const int TIL = NN / 4;  // 12500 exact
  for (int tile = blockIdx.x; tile < TIL; tile += gridDim.x) {
    int nb = tile * 4;
    float acc[4] = {0.f, 0.f, 0.f, 0.f};
#pragma unroll 2
    for (int t = 0; t < HID; t += 4) {
      float w0 = ws[t * (NH * HID) + col];
      float w1 = ws[(t + 1) * (NH * HID) + col];
      float w2 = ws[(t + 2) * (NH * HID) + col];
      float w3 = ws[(t + 3) * (NH * HID) + col];
#pragma unroll
      for (int j = 0; j < 4; ++j) {
        float4 xv = *(const float4*)(h1 + (size_t)(nb + j) * HID + t);
        acc[j] += xv.x * w0 + xv.y * w1 + xv.z * w2 + xv.w * w3;
      }
    }
#pragma unroll
    for (int j = 0; j < 4; ++j) {
      int n = nb + j;
      f[(size_t)n * (NH * HID) + col] = acc[j];
      float pe = acc[j] * alv, pr = acc[j] * arv;
#pragma unroll
      for (int off = 32; off; off >>= 1) {
        pe += __shfl_xor(pe, off);
        pr += __shfl_xor(pr, off);
      }
      if ((col & 63) == 0) {
        el[n * NH + h] = pe;
        er[n * NH + h] = pr;
      }
    }
  }
}

// ======== GAT gather: single-pass softmax (no max; |e| small) ========
// alpha = exp(e)/(sum exp(e)+1e-9): identical to ref within ~1e-10.
__global__ void k_gatg(const int* __restrict__ offs, const int* __restrict__ degd,
                       const int* __restrict__ esrc, const float* __restrict__ f,
                       const float* __restrict__ el, const float* __restrict__ er,
                       float* __restrict__ gat, int r, int accf) {
  int node = blockIdx.x * 4 + (threadIdx.x >> 6);
  int lane = threadIdx.x & 63;
  if (node >= NN) return;
  int start = offs[r * NN + node];
  int deg = degd[r * NN + node];
  float erv[NH];
#pragma unroll
  for (int h = 0; h < NH; ++h) erv[h] = er[node * NH + h];
  float z[NH] = {0.f, 0.f, 0.f};
  float acc[NH] = {0.f, 0.f, 0.f};
  for (int j = 0; j < deg; ++j) {
    int s = esrc[start + j];
#pragma unroll
    for (int h = 0; h < NH; ++h) {
      float ev = el[s * NH + h] + erv[h];
      ev = ev > 0.f ? ev : 0.2f * ev;
      float w = __expf(ev);
      z[h] += w;
      acc[h] += w * f[(size_t)s * (NH * HID) + h * HID + lane];
    }
  }
#pragma unroll
  for (int h = 0; h < NH; ++h) {
    float outv = acc[h] / (z[h] + 1e-9f);
    size_t idx = (size_t)node * (NH * HID) + h * HID + lane;
    gat[idx] = (accf ? gat[idx] : 0.f) + outv;
  }
}

// ======== conv2 matmul with fused relu(gat + sum_bg) on input read ========
__global__ __launch_bounds__(256, 4) void k_mm2v(const float* __restrict__ g,
                                                 const float* __restrict__ W2,
                                                 const float* __restrict__ bg,
                                                 const float* __restrict__ ns,
                                                 float* __restrict__ hw, int r) {
  __shared__ __align__(16) float ws[HID * FOUT];  // 16 KB
  __shared__ __align__(16) float bgs[NH * HID];   // 768 B
  {
    const float4* wsrc = (const float4*)(W2 + (size_t)r * HID * FOUT);
    float4* wdst = (float4*)ws;
#pragma unroll
    for (int i = 0; i < 4; ++i) wdst[threadIdx.x + i * 256] = wsrc[threadIdx.x + i * 256];
    if (threadIdx.x < NH * HID)
      bgs[threadIdx.x] = bg[threadIdx.x] + bg[NH * HID + threadIdx.x] +
                         bg[2 * NH * HID + threadIdx.x];
  }
  __syncthreads();
  int lane = threadIdx.x & 63, wv = threadIdx.x >> 6;
  const int ROWS = NN * NH;
  const int TIL = ROWS / 16;  // 9375 exact
  for (int tile = blockIdx.x; tile < TIL; tile += gridDim.x) {
    int rb = tile * 16 + wv * 4;
    float acc[4] = {0.f, 0.f, 0.f, 0.f};
#pragma unroll 2
    for (int t = 0; t < HID; t += 4) {
      float w0 = ws[t * FOUT + lane];
      float w1 = ws[(t + 1) * FOUT + lane];
      float w2 = ws[(t + 2) * FOUT + lane];
      float w3 = ws[(t + 3) * FOUT + lane];
#pragma unroll
      for (int j = 0; j < 4; ++j) {
        int row = rb + j;
        int h = row % NH;
        float4 xv = *(const float4*)(g + (size_t)row * HID + t);
        const float4 bv = *(const float4*)(bgs + h * HID + t);
        float vx = fmaxf(xv.x + bv.x, 0.f);
        float vy = fmaxf(xv.y + bv.y, 0.f);
        float vz = fmaxf(xv.z + bv.z, 0.f);
        float vw = fmaxf(xv.w + bv.w, 0.f);
        acc[j] += vx * w0 + vy * w1 + vz * w2 + vw * w3;
      }
    }
#pragma unroll
    for (int j = 0; j < 4; ++j) {
      int row = rb + j;
      int n = row / NH;
      hw[(size_t)row * FOUT + lane] = acc[j] * ns[r * NN + n];
    }
  }
}

// ======== conv2 gather; on final relation fuse +sum_b2 and sigmoid ========
__global__ void k_g2(const int* __restrict__ offs, const int* __restrict__ degd,
                     const int* __restrict__ esrc, const float* __restrict__ hw,
                     const float* __restrict__ nd, const float* __restrict__ b2,
                     float* __restrict__ agg2, int r, int accf, int fin) {
  int node = blockIdx.x * 4 + (threadIdx.x >> 6);
  int lane = threadIdx.x & 63;
  if (node >= NN) return;
  int start = offs[r * NN + node];
  int deg = degd[r * NN + node];
  float acc[NH] = {0.f, 0.f, 0.f};
  for (int j = 0; j < deg; ++j) {
    int s = esrc[start + j];
#pragma unroll
    for (int h = 0; h < NH; ++h)
      acc[h] += hw[(size_t)s * (NH * FOUT) + h * FOUT + lane];
  }
  float ndv = nd[r * NN + node];
  float b2s = fin ? (b2[lane] + b2[FOUT + lane] + b2[2 * FOUT + lane]) : 0.f;
#pragma unroll
  for (int h = 0; h < NH; ++h) {
    size_t idx = (size_t)node * (NH * FOUT) + h * FOUT + lane;
    float v = (accf ? agg2[idx] : 0.f) + acc[h] * ndv;
    if (fin) v = 1.0f / (1.0f + __expf(-(v + b2s)));
    agg2[idx] = v;
  }
}

__global__ void k_cnt2(const int* __restrict__ gid, float* __restrict__ cnt) {
  __shared__ int loc[NB];
  if (threadIdx.x < NB) loc[threadIdx.x] = 0;
  __syncthreads();
  int i = blockIdx.x * 256 + threadIdx.x;
  if (i < NN) atomicAdd(&loc[gid[i]], 1);
  __syncthreads();
  if (threadIdx.x < NB) atomicAdd(&cnt[threadIdx.x], (float)loc[threadIdx.x]);
}

__global__ void k_pool(const float* __restrict__ h3, const int* __restrict__ gid,
                       float* __restrict__ pooled) {
  int j = threadIdx.x;  // 0..191
  int start = blockIdx.x * 128;
  if (start >= NN) return;
  int end = start + 128;
  if (end > NN) end = NN;
  int gcur = gid[start];
  float acc = 0.f;
  for (int n = start; n < end; ++n) {
    int g = gid[n];
    if (g != gcur) {
      atomicAdd(&pooled[gcur * (NH * FOUT) + j], acc);
      acc = 0.f;
      gcur = g;
    }
    acc += h3[(size_t)n * (NH * FOUT) + j];
  }
  atomicAdd(&pooled[gcur * (NH * FOUT) + j], acc);
}

__global__ void k_final(const float* __restrict__ pooled, const float* __restrict__ cnt,
                        const float* __restrict__ Wc, const float* __restrict__ bc,
                        float* __restrict__ out) {
  int t = threadIdx.x;
  if (t >= NB * NH) return;
  int b = t / NH;
  float inv = 1.0f / fmaxf(cnt[b], 1.0f);
  const float* p = pooled + t * FOUT;
  float sacc = 0.f;
  for (int c = 0; c < NC; ++c) {
    float acc = bc[c];
    for (int o = 0; o < FOUT; ++o) acc += p[o] * inv * Wc[o * NC + c];
    sacc += 1.0f / (1.0f + __expf(-acc));
  }
  out[t] = sacc * (1.0f / NC);
}

extern "C" void kernel_launch(void* const* d_in, const int* in_sizes, int n_in,
                              void* d_out, int out_size, void* d_ws, size_t ws_size,
                              hipStream_t stream) {
  const float* x = (const float*)d_in[0];
  const int* src = (const int*)d_in[1];
  const int* dst = (const int*)d_in[2];
  const int* gid = (const int*)d_in[3];
  const float* W1 = (const float*)d_in[4];
  const float* b1 = (const float*)d_in[5];
  const float* Wg = (const float*)d_in[6];
  const float* al = (const float*)d_in[7];
  const float* ar = (const float*)d_in[8];
  const float* bg = (const float*)d_in[9];
  const float* W2 = (const float*)d_in[10];
  const float* b2 = (const float*)d_in[11];
  const float* Wc = (const float*)d_in[12];
  const float* bc = (const float*)d_in[13];
  float* out = (float*)d_out;

  // ---- workspace layout ----
  int* degs = (int*)d_ws;                        // RR*NN
  int* degd = degs + RR * NN;                    // RR*NN
  float* cnt = (float*)(degd + RR * NN);         // NB
  float* pooled = cnt + NB;                      // NB*NH*FOUT
  size_t zero_bytes = ((size_t)2 * RR * NN + NB + NB * NH * FOUT) * 4;
  int* offs = (int*)(pooled + NB * NH * FOUT);   // RR*NN (+1 pad)
  int* cursor = offs + RR * NN + 1;              // RR*NN
  int* bsum = cursor + RR * NN;                  // 1024
  int* esrc = bsum + 1024;                       // RR*EE
  float* ns = (float*)(esrc + (size_t)RR * EE);  // RR*NN
  float* nd = ns + RR * NN;                      // RR*NN
  float* el = nd + RR * NN;                      // NN*NH
  float* er = el + NN * NH;                      // NN*NH
  float* h1 = er + NN * NH;                      // NN*HID
  float* gat = h1 + (size_t)NN * HID;            // NN*NH*HID
  float* agg2 = gat + (size_t)NN * NH * HID;     // NN*NH*FOUT
  float* A = agg2 + (size_t)NN * NH * FOUT;      // 9.6M floats staging

  hipMemsetAsync(d_ws, 0, zero_bytes, stream);

  const int nscan = RR * NN;
  const int nblk1 = (nscan + 255) / 256;

  // degrees + norms + CSR build
  k_deg<<<(RR * EE + 255) / 256, 256, 0, stream>>>(src, dst, degs, degd);
  k_norm<<<(nscan + 255) / 256, 256, 0, stream>>>(degs, degd, ns, nd);
  k_scan1<<<nblk1, 256, 0, stream>>>(degd, offs, bsum);
  k_scan2<<<1, 1024, 0, stream>>>(bsum, nblk1);
  k_scan3<<<nblk1, 256, 0, stream>>>(offs, bsum, cursor);
  k_fill<<<(RR * EE + 255) / 256, 256, 0, stream>>>(src, dst, cursor, esrc);

  // conv1: LDS-staged matmul (grid.y = relation) + gather+bias+L2norm
  k_mm1v<<<dim3(256, RR), 256, 0, stream>>>(x, W1, ns, A);
  k_g1<<<(NN + 3) / 4, 256, 0, stream>>>(offs, degd, esrc, A, nd, b1, h1);

  // GAT per relation: matmul+el/er fused, then single-pass gather softmax
  for (int r = 0; r < RR; ++r) {
    k_mmgv<<<768, 192, 0, stream>>>(h1, Wg, al, ar, A, el, er, r);
    k_gatg<<<(NN + 3) / 4, 256, 0, stream>>>(offs, degd, esrc, A, el, er, gat, r, r != 0);
  }

  // conv2 per relation: relu+bg fused into matmul read; sigmoid+b2 on final
  for (int r = 0; r < RR; ++r) {
    k_mm2v<<<768, 256, 0, stream>>>(gat, W2, bg, ns, A, r);
    k_g2<<<(NN + 3) / 4, 256, 0, stream>>>(offs, degd, esrc, A, nd, b2, agg2, r,
                                           r != 0, r == RR - 1);
  }

  // pooling + classifier
  k_cnt2<<<(NN + 255) / 256, 256, 0, stream>>>(gid, cnt);
  k_pool<<<(NN + 127) / 128, 192, 0, stream>>>(agg2, gid, pooled);
  k_final<<<1, 64, 0, stream>>>(pooled, cnt, Wc, bc, out);
}

// Round 6
// 999.638 us; speedup vs baseline: 2.1799x; 1.5145x over previous
//
#include <hip/hip_runtime.h>
#include <math.h>

#define NN 50000
#define EE 400000
#define RR 3
#define NH 3
#define FIN 128
#define HID 64
#define FOUT 64
#define NC 16
#define NB 8

typedef __attribute__((ext_vector_type(8))) short v8s;  // 8 bf16 (4 VGPRs)
typedef __attribute__((ext_vector_type(4))) float v4f;  // MFMA acc
typedef unsigned short u16;
typedef __attribute__((ext_vector_type(4))) unsigned short u16x4;

__device__ __forceinline__ u16 f2b(float f) {  // f32 -> bf16 RNE
  unsigned u = __float_as_uint(f);
  return (u16)((u + 0x7fffu + ((u >> 16) & 1u)) >> 16);
}
__device__ __forceinline__ float b2f(u16 b) {
  return __uint_as_float(((unsigned)b) << 16);
}

// ======== degree histogram ========
__global__ void k_deg(const int* __restrict__ src, const int* __restrict__ dst,
                      int* __restrict__ degs, int* __restrict__ degd) {
  int i = blockIdx.x * 256 + threadIdx.x;
  if (i >= RR * EE) return;
  int r = i / EE;
  atomicAdd(&degs[r * NN + src[i]], 1);
  atomicAdd(&degd[r * NN + dst[i]], 1);
}

__global__ void k_norm(const int* __restrict__ degs, const int* __restrict__ degd,
                       float* __restrict__ ns, float* __restrict__ nd) {
  int i = blockIdx.x * 256 + threadIdx.x;
  if (i >= RR * NN) return;
  ns[i] = 1.0f / sqrtf((float)(degs[i] > 1 ? degs[i] : 1));
  nd[i] = 1.0f / sqrtf((float)(degd[i] > 1 ? degd[i] : 1));
}

// ======== exclusive scan (3 kernels) ========
__global__ void k_scan1(const int* __restrict__ deg, int* __restrict__ offs,
                        int* __restrict__ bsum) {
  __shared__ int sh[256];
  int gid = blockIdx.x * 256 + threadIdx.x;
  int v = (gid < RR * NN) ? deg[gid] : 0;
  sh[threadIdx.x] = v;
  __syncthreads();
  for (int off = 1; off < 256; off <<= 1) {
    int t = (threadIdx.x >= off) ? sh[threadIdx.x - off] : 0;
    __syncthreads();
    sh[threadIdx.x] += t;
    __syncthreads();
  }
  if (gid < RR * NN) offs[gid] = sh[threadIdx.x] - v;
  if (threadIdx.x == 255) bsum[blockIdx.x] = sh[255];
}

__global__ void k_scan2(int* __restrict__ bsum, int nb) {
  __shared__ int sh[1024];
  int v = (threadIdx.x < nb) ? bsum[threadIdx.x] : 0;
  sh[threadIdx.x] = v;
  __syncthreads();
  for (int off = 1; off < 1024; off <<= 1) {
    int t = (threadIdx.x >= off) ? sh[threadIdx.x - off] : 0;
    __syncthreads();
    sh[threadIdx.x] += t;
    __syncthreads();
  }
  if (threadIdx.x < nb) bsum[threadIdx.x] = sh[threadIdx.x] - v;
}

__global__ void k_scan3(int* __restrict__ offs, const int* __restrict__ bsum,
                        int* __restrict__ cursor) {
  int i = blockIdx.x * 256 + threadIdx.x;
  if (i >= RR * NN) return;
  int v = offs[i] + bsum[i / 256];
  offs[i] = v;
  cursor[i] = v;
}

__global__ void k_fill(const int* __restrict__ src, const int* __restrict__ dst,
                       int* __restrict__ cursor, int* __restrict__ esrc) {
  int i = blockIdx.x * 256 + threadIdx.x;
  if (i >= RR * EE) return;
  int r = i / EE;
  int d = dst[i];
  int pos = atomicAdd(&cursor[r * NN + d], 1);
  esrc[pos] = src[i];
}

// ======== f32 -> bf16 cast (vectorized) ========
__global__ void k_cast(const float4* __restrict__ in, u16x4* __restrict__ out, int n4) {
  int i = blockIdx.x * 256 + threadIdx.x;
  if (i >= n4) return;
  float4 v = in[i];
  u16x4 o;
  o.x = f2b(v.x); o.y = f2b(v.y); o.z = f2b(v.z); o.w = f2b(v.w);
  out[i] = o;
}

// ======== Wgal/Wgar precompute: [r][k][h] = sum_c Wg[r][k][h*64+c]*al[r][h][c]
__global__ void k_wgal(const float* __restrict__ Wg, const float* __restrict__ al,
                       const float* __restrict__ ar, float* __restrict__ Wgal,
                       float* __restrict__ Wgar) {
  int t = threadIdx.x;
  if (t >= RR * HID * NH) return;  // 576
  int r = t / (HID * NH);
  int rem = t % (HID * NH);
  int k = rem / NH, h = rem % NH;
  const float* wg = Wg + ((size_t)(r * HID + k)) * (NH * HID) + h * HID;
  const float* alp = al + (r * NH + h) * HID;
  const float* arp = ar + (r * NH + h) * HID;
  float a = 0.f, b = 0.f;
#pragma unroll 8
  for (int c = 0; c < HID; ++c) { a += wg[c] * alp[c]; b += wg[c] * arp[c]; }
  Wgal[t] = a;
  Wgar[t] = b;
}

// ======== MFMA GEMM: C[M][N](bf16) = rowscale * A[M][K](bf16) @ B[K][N](f32->bf16)
// SCALE_MODE: 0 none, 1 scale[row], 2 scale[row/3]
// gridDim.y = relations; B += y*bstr, C += y*cstr, scale += y*sstr
template <int K, int N, int SCALE_MODE>
__global__ __launch_bounds__(256) void k_gemm(const u16* __restrict__ A,
                                              const float* __restrict__ B0, int bstr,
                                              u16* __restrict__ C0, long cstr,
                                              const float* __restrict__ s0, int sstr,
                                              int M) {
  constexpr int KP = K + 8;  // pad: lane stride (K+8)*2B -> 2-way bank alias (free)
  __shared__ __align__(16) u16 Bt[N * KP];
  const float* B = B0 + (size_t)blockIdx.y * bstr;
  u16* C = C0 + (size_t)blockIdx.y * cstr;
  const float* scale = s0 + (size_t)blockIdx.y * sstr;
  for (int i = threadIdx.x; i < K * N; i += 256) {
    int k = i / N, n = i % N;
    Bt[n * KP + k] = f2b(B[(size_t)k * N + n]);
  }
  __syncthreads();
  int wid = threadIdx.x >> 6, lane = threadIdx.x & 63;
  int l15 = lane & 15, lg = lane >> 4;
  constexpr int NT = N / 16;
  int ntiles = (M + 63) >> 6;
  for (int tile = blockIdx.x; tile < ntiles; tile += gridDim.x) {
    int mbase = tile * 64 + wid * 16;
    v4f acc[NT];
#pragma unroll
    for (int t = 0; t < NT; ++t) acc[t] = (v4f)(0.f);
    int arow = mbase + l15;
    if (arow >= M) arow = M - 1;
    const u16* ap = A + (size_t)arow * K + lg * 8;
#pragma unroll
    for (int ks = 0; ks < K / 32; ++ks) {
      v8s a = *(const v8s*)(ap + ks * 32);
#pragma unroll
      for (int t = 0; t < NT; ++t) {
        v8s b = *(const v8s*)(&Bt[(t * 16 + l15) * KP + lg * 8 + ks * 32]);
        acc[t] = __builtin_amdgcn_mfma_f32_16x16x32_bf16(a, b, acc[t], 0, 0, 0);
      }
    }
#pragma unroll
    for (int q = 0; q < 4; ++q) {
      int row = mbase + lg * 4 + q;
      if (row < M) {
        float s = 1.f;
        if (SCALE_MODE == 1) s = scale[row];
        if (SCALE_MODE == 2) s = scale[row / NH];
#pragma unroll
        for (int t = 0; t < NT; ++t)
          C[(size_t)row * N + t * 16 + l15] = f2b(acc[t][q] * s);
      }
    }
  }
}

// ======== conv1 gather + bias + L2 normalize -> h1b (bf16) ========
__global__ void k_g1(const int* __restrict__ offs, const int* __restrict__ degd,
                     const int* __restrict__ esrc, const u16* __restrict__ hw,
                     const float* __restrict__ nd, const float* __restrict__ b1,
                     u16* __restrict__ h1b) {
  int node = blockIdx.x * 4 + (threadIdx.x >> 6);
  int lane = threadIdx.x & 63;
  if (node >= NN) return;
  float v = 0.f;
#pragma unroll
  for (int r = 0; r < RR; ++r) {
    int start = offs[r * NN + node];
    int deg = degd[r * NN + node];
    float t = 0.f;
    for (int j = 0; j < deg; ++j) {
      int s = esrc[start + j];
      t += b2f(hw[((size_t)r * NN + s) * HID + lane]);
    }
    v += t * nd[r * NN + node];
  }
  v += b1[lane] + b1[HID + lane] + b1[2 * HID + lane];
  float sq = v * v;
  for (int off = 32; off; off >>= 1) sq += __shfl_xor(sq, off);
  float nrm = sqrtf(sq);
  nrm = nrm > 1e-12f ? nrm : 1e-12f;
  h1b[node * HID + lane] = f2b(v / nrm);
}

// ======== el/er for all relations: el[r][n][h] = sum_k h1[n][k]*Wgal[r][k][h]
__global__ void k_eler(const u16* __restrict__ h1b, const float* __restrict__ Wgal,
                       const float* __restrict__ Wgar, float* __restrict__ el,
                       float* __restrict__ er) {
  int node = blockIdx.x * 4 + (threadIdx.x >> 6);
  int lane = threadIdx.x & 63;
  if (node >= NN) return;
  float hv = b2f(h1b[node * HID + lane]);
#pragma unroll
  for (int r = 0; r < RR; ++r) {
#pragma unroll
    for (int h = 0; h < NH; ++h) {
      float a = hv * Wgal[(r * HID + lane) * NH + h];
      float b = hv * Wgar[(r * HID + lane) * NH + h];
#pragma unroll
      for (int off = 32; off; off >>= 1) {
        a += __shfl_xor(a, off);
        b += __shfl_xor(b, off);
      }
      if (lane == 0) {
        el[((size_t)r * NN + node) * NH + h] = a;
        er[((size_t)r * NN + node) * NH + h] = b;
      }
    }
  }
}

// ======== GAT gather (bf16 f); fin fuses +sum_bg, relu -> gatb bf16 ========
__global__ void k_gatg(const int* __restrict__ offs, const int* __restrict__ degd,
                       const int* __restrict__ esrc, const u16* __restrict__ f,
                       const float* __restrict__ el, const float* __restrict__ er,
                       float* __restrict__ gat, u16* __restrict__ gatb,
                       const float* __restrict__ bg, int r, int accf, int fin) {
  int node = blockIdx.x * 4 + (threadIdx.x >> 6);
  int lane = threadIdx.x & 63;
  if (node >= NN) return;
  int start = offs[r * NN + node];
  int deg = degd[r * NN + node];
  float erv[NH];
#pragma unroll
  for (int h = 0; h < NH; ++h) erv[h] = er[node * NH + h];
  float z[NH] = {0.f, 0.f, 0.f};
  float acc[NH] = {0.f, 0.f, 0.f};
  for (int j = 0; j < deg; ++j) {
    int s = esrc[start + j];
#pragma unroll
    for (int h = 0; h < NH; ++h) {
      float ev = el[s * NH + h] + erv[h];
      ev = ev > 0.f ? ev : 0.2f * ev;
      float w = __expf(ev);
      z[h] += w;
      acc[h] += w * b2f(f[(size_t)s * (NH * HID) + h * HID + lane]);
    }
  }
#pragma unroll
  for (int h = 0; h < NH; ++h) {
    size_t idx = (size_t)node * (NH * HID) + h * HID + lane;
    float v = (accf ? gat[idx] : 0.f) + acc[h] / (z[h] + 1e-9f);
    if (fin) {
      int j = h * HID + lane;
      v += bg[j] + bg[NH * HID + j] + bg[2 * NH * HID + j];
      gatb[idx] = f2b(fmaxf(v, 0.f));
    } else {
      gat[idx] = v;
    }
  }
}

// ======== conv2 gather; fin fuses +sum_b2, sigmoid ========
__global__ void k_g2(const int* __restrict__ offs, const int* __restrict__ degd,
                     const int* __restrict__ esrc, const u16* __restrict__ hw,
                     const float* __restrict__ nd, const float* __restrict__ b2,
                     float* __restrict__ agg2, int r, int accf, int fin) {
  int node = blockIdx.x * 4 + (threadIdx.x >> 6);
  int lane = threadIdx.x & 63;
  if (node >= NN) return;
  int start = offs[r * NN + node];
  int deg = degd[r * NN + node];
  float acc[NH] = {0.f, 0.f, 0.f};
  for (int j = 0; j < deg; ++j) {
    int s = esrc[start + j];
#pragma unroll
    for (int h = 0; h < NH; ++h)
      acc[h] += b2f(hw[(size_t)s * (NH * FOUT) + h * FOUT + lane]);
  }
  float ndv = nd[r * NN + node];
  float b2s = fin ? (b2[lane] + b2[FOUT + lane] + b2[2 * FOUT + lane]) : 0.f;
#pragma unroll
  for (int h = 0; h < NH; ++h) {
    size_t idx = (size_t)node * (NH * FOUT) + h * FOUT + lane;
    float v = (accf ? agg2[idx] : 0.f) + acc[h] * ndv;
    if (fin) v = 1.0f / (1.0f + __expf(-(v + b2s)));
    agg2[idx] = v;
  }
}

__global__ void k_cnt2(const int* __restrict__ gid, float* __restrict__ cnt) {
  __shared__ int loc[NB];
  if (threadIdx.x < NB) loc[threadIdx.x] = 0;
  __syncthreads();
  int i = blockIdx.x * 256 + threadIdx.x;
  if (i < NN) atomicAdd(&loc[gid[i]], 1);
  __syncthreads();
  if (threadIdx.x < NB) atomicAdd(&cnt[threadIdx.x], (float)loc[threadIdx.x]);
}

__global__ void k_pool(const float* __restrict__ h3, const int* __restrict__ gid,
                       float* __restrict__ pooled) {
  int j = threadIdx.x;  // 0..191
  int start = blockIdx.x * 128;
  if (start >= NN) return;
  int end = start + 128;
  if (end > NN) end = NN;
  int gcur = gid[start];
  float acc = 0.f;
  for (int n = start; n < end; ++n) {
    int g = gid[n];
    if (g != gcur) {
      atomicAdd(&pooled[gcur * (NH * FOUT) + j], acc);
      acc = 0.f;
      gcur = g;
    }
    acc += h3[(size_t)n * (NH * FOUT) + j];
  }
  atomicAdd(&pooled[gcur * (NH * FOUT) + j], acc);
}

__global__ void k_final(const float* __restrict__ pooled, const float* __restrict__ cnt,
                        const float* __restrict__ Wc, const float* __restrict__ bc,
                        float* __restrict__ out) {
  int t = threadIdx.x;
  if (t >= NB * NH) return;
  int b = t / NH;
  float inv = 1.0f / fmaxf(cnt[b], 1.0f);
  const float* p = pooled + t * FOUT;
  float sacc = 0.f;
  for (int c = 0; c < NC; ++c) {
    float acc = bc[c];
    for (int o = 0; o < FOUT; ++o) acc += p[o] * inv * Wc[o * NC + c];
    sacc += 1.0f / (1.0f + __expf(-acc));
  }
  out[t] = sacc * (1.0f / NC);
}

extern "C" void kernel_launch(void* const* d_in, const int* in_sizes, int n_in,
                              void* d_out, int out_size, void* d_ws, size_t ws_size,
                              hipStream_t stream) {
  const float* x = (const float*)d_in[0];
  const int* src = (const int*)d_in[1];
  const int* dst = (const int*)d_in[2];
  const int* gid = (const int*)d_in[3];
  const float* W1 = (const float*)d_in[4];
  const float* b1 = (const float*)d_in[5];
  const float* Wg = (const float*)d_in[6];
  const float* al = (const float*)d_in[7];
  const float* ar = (const float*)d_in[8];
  const float* bg = (const float*)d_in[9];
  const float* W2 = (const float*)d_in[10];
  const float* b2 = (const float*)d_in[11];
  const float* Wc = (const float*)d_in[12];
  const float* bc = (const float*)d_in[13];
  float* out = (float*)d_out;

  // ---- workspace layout (all offsets 16B-aligned) ----
  int* degs = (int*)d_ws;                         // 150000
  int* degd = degs + RR * NN;                     // 150000
  float* cnt = (float*)(degd + RR * NN);          // 8
  float* pooled = cnt + NB;                       // 1536
  size_t zero_bytes = ((size_t)2 * RR * NN + NB + NB * NH * FOUT) * 4;
  int* offs = (int*)(pooled + NB * NH * FOUT);    // 150008 (padded)
  int* cursor = offs + RR * NN + 8;               // 150000
  int* bsum = cursor + RR * NN;                   // 1024
  int* esrc = bsum + 1024;                        // 1200000
  float* ns = (float*)(esrc + (size_t)RR * EE);   // 150000
  float* nd = ns + RR * NN;                       // 150000
  float* el = nd + RR * NN;                       // 450000
  float* er = el + (size_t)RR * NN * NH;          // 450000
  float* Wgal = er + (size_t)RR * NN * NH;        // 576
  float* Wgar = Wgal + RR * HID * NH;             // 576
  float* gat = Wgar + RR * HID * NH;              // 9600000 f32
  float* agg2 = gat;                              // alias: gat free after fin gatg
  u16* xb = (u16*)(gat + (size_t)NN * NH * HID);  // 6400000 u16
  u16* h1b = xb + (size_t)NN * FIN;               // 3200000
  u16* gatb = h1b + (size_t)NN * HID;             // 9600000
  u16* S = gatb + (size_t)NN * NH * HID;          // 9600000 (shared staging)

  hipMemsetAsync(d_ws, 0, zero_bytes, stream);

  const int nscan = RR * NN;
  const int nblk1 = (nscan + 255) / 256;

  // degrees + norms + CSR build
  k_deg<<<(RR * EE + 255) / 256, 256, 0, stream>>>(src, dst, degs, degd);
  k_norm<<<(nscan + 255) / 256, 256, 0, stream>>>(degs, degd, ns, nd);
  k_scan1<<<nblk1, 256, 0, stream>>>(degd, offs, bsum);
  k_scan2<<<1, 1024, 0, stream>>>(bsum, nblk1);
  k_scan3<<<nblk1, 256, 0, stream>>>(offs, bsum, cursor);
  k_fill<<<(RR * EE + 255) / 256, 256, 0, stream>>>(src, dst, cursor, esrc);

  // casts + tiny precompute
  k_cast<<<(NN * FIN / 4 + 255) / 256, 256, 0, stream>>>((const float4*)x, (u16x4*)xb,
                                                         NN * FIN / 4);
  k_wgal<<<1, 576, 0, stream>>>(Wg, al, ar, Wgal, Wgar);

  // conv1: MFMA GEMM (grid.y=relation) + gather+bias+L2norm
  k_gemm<FIN, HID, 1><<<dim3(782, RR), 256, 0, stream>>>(
      xb, W1, FIN * HID, S, (long)NN * HID, ns, NN, NN);
  k_g1<<<(NN + 3) / 4, 256, 0, stream>>>(offs, degd, esrc, S, nd, b1, h1b);

  // el/er for all relations (via Wgal/Wgar)
  k_eler<<<(NN + 3) / 4, 256, 0, stream>>>(h1b, Wgal, Wgar, el, er);

  // GAT per relation: MFMA GEMM -> S, then gather softmax
  for (int r = 0; r < RR; ++r) {
    k_gemm<HID, NH * HID, 0><<<dim3(782, 1), 256, 0, stream>>>(
        h1b, Wg + (size_t)r * HID * NH * HID, 0, S, 0, ns, 0, NN);
    k_gatg<<<(NN + 3) / 4, 256, 0, stream>>>(offs, degd, esrc, S,
                                             el + (size_t)r * NN * NH,
                                             er + (size_t)r * NN * NH, gat, gatb, bg,
                                             r, r != 0, r == RR - 1);
  }

  // conv2 per relation: MFMA GEMM (rows = n*NH+h) -> S, then gather
  for (int r = 0; r < RR; ++r) {
    k_gemm<HID, FOUT, 2><<<dim3(2344, 1), 256, 0, stream>>>(
        gatb, W2 + (size_t)r * HID * FOUT, 0, S, 0, ns + (size_t)r * NN, 0, NN * NH);
    k_g2<<<(NN + 3) / 4, 256, 0, stream>>>(offs, degd, esrc, S, nd, b2, agg2, r,
                                           r != 0, r == RR - 1);
  }

  // pooling + classifier
  k_cnt2<<<(NN + 255) / 256, 256, 0, stream>>>(gid, cnt);
  k_pool<<<(NN + 127) / 128, 192, 0, stream>>>(agg2, gid, pooled);
  k_final<<<1, 64, 0, stream>>>(pooled, cnt, Wc, bc, out);
}

// Round 7
// 757.350 us; speedup vs baseline: 2.8773x; 1.3199x over previous
//
#include <hip/hip_runtime.h>
#include <math.h>

#define NN 50000
#define EE 400000
#define RR 3
#define NH 3
#define FIN 128
#define HID 64
#define FOUT 64
#define NC 16
#define NB 8

typedef __attribute__((ext_vector_type(8))) short v8s;  // 8 bf16 (4 VGPRs)
typedef __attribute__((ext_vector_type(4))) float v4f;  // MFMA acc
typedef unsigned short u16;
typedef __attribute__((ext_vector_type(4))) unsigned short u16x4;

__device__ __forceinline__ u16 f2b(float f) {  // f32 -> bf16 RNE
  unsigned u = __float_as_uint(f);
  return (u16)((u + 0x7fffu + ((u >> 16) & 1u)) >> 16);
}
__device__ __forceinline__ float b2f(u16 b) {
  return __uint_as_float(((unsigned)b) << 16);
}
__device__ __forceinline__ float wexp(float e) {  // leaky_relu(0.2) then exp
  e = e > 0.f ? e : 0.2f * e;
  return __expf(e);
}

// ======== degree histogram ========
__global__ void k_deg(const int* __restrict__ src, const int* __restrict__ dst,
                      int* __restrict__ degs, int* __restrict__ degd) {
  int i = blockIdx.x * 256 + threadIdx.x;
  if (i >= RR * EE) return;
  int r = i / EE;
  atomicAdd(&degs[r * NN + src[i]], 1);
  atomicAdd(&degd[r * NN + dst[i]], 1);
}

__global__ void k_norm(const int* __restrict__ degs, const int* __restrict__ degd,
                       float* __restrict__ ns, float* __restrict__ nd) {
  int i = blockIdx.x * 256 + threadIdx.x;
  if (i >= RR * NN) return;
  ns[i] = 1.0f / sqrtf((float)(degs[i] > 1 ? degs[i] : 1));
  nd[i] = 1.0f / sqrtf((float)(degd[i] > 1 ? degd[i] : 1));
}

// ======== exclusive scan (3 kernels) ========
__global__ void k_scan1(const int* __restrict__ deg, int* __restrict__ offs,
                        int* __restrict__ bsum) {
  __shared__ int sh[256];
  int gid = blockIdx.x * 256 + threadIdx.x;
  int v = (gid < RR * NN) ? deg[gid] : 0;
  sh[threadIdx.x] = v;
  __syncthreads();
  for (int off = 1; off < 256; off <<= 1) {
    int t = (threadIdx.x >= off) ? sh[threadIdx.x - off] : 0;
    __syncthreads();
    sh[threadIdx.x] += t;
    __syncthreads();
  }
  if (gid < RR * NN) offs[gid] = sh[threadIdx.x] - v;
  if (threadIdx.x == 255) bsum[blockIdx.x] = sh[255];
}

__global__ void k_scan2(int* __restrict__ bsum, int nb) {
  __shared__ int sh[1024];
  int v = (threadIdx.x < nb) ? bsum[threadIdx.x] : 0;
  sh[threadIdx.x] = v;
  __syncthreads();
  for (int off = 1; off < 1024; off <<= 1) {
    int t = (threadIdx.x >= off) ? sh[threadIdx.x - off] : 0;
    __syncthreads();
    sh[threadIdx.x] += t;
    __syncthreads();
  }
  if (threadIdx.x < nb) bsum[threadIdx.x] = sh[threadIdx.x] - v;
}

__global__ void k_scan3(int* __restrict__ offs, const int* __restrict__ bsum,
                        int* __restrict__ cursor) {
  int i = blockIdx.x * 256 + threadIdx.x;
  if (i >= RR * NN) return;
  int v = offs[i] + bsum[i / 256];
  offs[i] = v;
  cursor[i] = v;
}

__global__ void k_fill(const int* __restrict__ src, const int* __restrict__ dst,
                       int* __restrict__ cursor, int* __restrict__ esrc) {
  int i = blockIdx.x * 256 + threadIdx.x;
  if (i >= RR * EE) return;
  int r = i / EE;
  int d = dst[i];
  int pos = atomicAdd(&cursor[r * NN + d], 1);
  esrc[pos] = src[i];
}

// ======== f32 -> bf16 cast ========
__global__ void k_cast(const float4* __restrict__ in, u16x4* __restrict__ out, int n4) {
  int i = blockIdx.x * 256 + threadIdx.x;
  if (i >= n4) return;
  float4 v = in[i];
  u16x4 o;
  o.x = f2b(v.x); o.y = f2b(v.y); o.z = f2b(v.z); o.w = f2b(v.w);
  out[i] = o;
}

// ======== Wgal/Wgar precompute ========
__global__ void k_wgal(const float* __restrict__ Wg, const float* __restrict__ al,
                       const float* __restrict__ ar, float* __restrict__ Wgal,
                       float* __restrict__ Wgar) {
  int t = threadIdx.x;
  if (t >= RR * HID * NH) return;  // 576
  int r = t / (HID * NH);
  int rem = t % (HID * NH);
  int k = rem / NH, h = rem % NH;
  const float* wg = Wg + ((size_t)(r * HID + k)) * (NH * HID) + h * HID;
  const float* alp = al + (r * NH + h) * HID;
  const float* arp = ar + (r * NH + h) * HID;
  float a = 0.f, b = 0.f;
#pragma unroll 8
  for (int c = 0; c < HID; ++c) { a += wg[c] * alp[c]; b += wg[c] * arp[c]; }
  Wgal[t] = a;
  Wgar[t] = b;
}

// ======== MFMA GEMM (verified mapping from R5) ========
template <int K, int N, int SCALE_MODE>
__global__ __launch_bounds__(256) void k_gemm(const u16* __restrict__ A,
                                              const float* __restrict__ B0, int bstr,
                                              u16* __restrict__ C0, long cstr,
                                              const float* __restrict__ s0, int sstr,
                                              int M) {
  constexpr int KP = K + 8;
  __shared__ __align__(16) u16 Bt[N * KP];
  const float* B = B0 + (size_t)blockIdx.y * bstr;
  u16* C = C0 + (size_t)blockIdx.y * cstr;
  const float* scale = s0 + (size_t)blockIdx.y * sstr;
  for (int i = threadIdx.x; i < K * N; i += 256) {
    int k = i / N, n = i % N;
    Bt[n * KP + k] = f2b(B[(size_t)k * N + n]);
  }
  __syncthreads();
  int wid = threadIdx.x >> 6, lane = threadIdx.x & 63;
  int l15 = lane & 15, lg = lane >> 4;
  constexpr int NT = N / 16;
  int ntiles = (M + 63) >> 6;
  for (int tile = blockIdx.x; tile < ntiles; tile += gridDim.x) {
    int mbase = tile * 64 + wid * 16;
    v4f acc[NT];
#pragma unroll
    for (int t = 0; t < NT; ++t) acc[t] = (v4f)(0.f);
    int arow = mbase + l15;
    if (arow >= M) arow = M - 1;
    const u16* ap = A + (size_t)arow * K + lg * 8;
#pragma unroll
    for (int ks = 0; ks < K / 32; ++ks) {
      v8s a = *(const v8s*)(ap + ks * 32);
#pragma unroll
      for (int t = 0; t < NT; ++t) {
        v8s b = *(const v8s*)(&Bt[(t * 16 + l15) * KP + lg * 8 + ks * 32]);
        acc[t] = __builtin_amdgcn_mfma_f32_16x16x32_bf16(a, b, acc[t], 0, 0, 0);
      }
    }
#pragma unroll
    for (int q = 0; q < 4; ++q) {
      int row = mbase + lg * 4 + q;
      if (row < M) {
        float s = 1.f;
        if (SCALE_MODE == 1) s = scale[row];
        if (SCALE_MODE == 2) s = scale[row / NH];
#pragma unroll
        for (int t = 0; t < NT; ++t)
          C[(size_t)row * N + t * 16 + l15] = f2b(acc[t][q] * s);
      }
    }
  }
}

// ======== conv1 gather (unroll 4) + bias + L2 normalize -> h1b ========
__global__ void k_g1(const int* __restrict__ offs, const int* __restrict__ degd,
                     const int* __restrict__ esrc, const u16* __restrict__ hw,
                     const float* __restrict__ nd, const float* __restrict__ b1,
                     u16* __restrict__ h1b) {
  int node = blockIdx.x * 4 + (threadIdx.x >> 6);
  int lane = threadIdx.x & 63;
  if (node >= NN) return;
  float v = 0.f;
#pragma unroll
  for (int r = 0; r < RR; ++r) {
    int start = offs[r * NN + node];
    int deg = degd[r * NN + node];
    const u16* base = hw + (size_t)r * NN * HID + lane;
    float t = 0.f;
    int j = 0;
    for (; j + 4 <= deg; j += 4) {
      int s0 = esrc[start + j], s1 = esrc[start + j + 1];
      int s2 = esrc[start + j + 2], s3 = esrc[start + j + 3];
      float a0 = b2f(base[(size_t)s0 * HID]);
      float a1 = b2f(base[(size_t)s1 * HID]);
      float a2 = b2f(base[(size_t)s2 * HID]);
      float a3 = b2f(base[(size_t)s3 * HID]);
      t += (a0 + a1) + (a2 + a3);
    }
    for (; j < deg; ++j) t += b2f(base[(size_t)esrc[start + j] * HID]);
    v += t * nd[r * NN + node];
  }
  v += b1[lane] + b1[HID + lane] + b1[2 * HID + lane];
  float sq = v * v;
  for (int off = 32; off; off >>= 1) sq += __shfl_xor(sq, off);
  float nrm = sqrtf(sq);
  nrm = nrm > 1e-12f ? nrm : 1e-12f;
  h1b[node * HID + lane] = f2b(v / nrm);
}

// ======== el/er for all relations ========
__global__ void k_eler(const u16* __restrict__ h1b, const float* __restrict__ Wgal,
                       const float* __restrict__ Wgar, float* __restrict__ el,
                       float* __restrict__ er) {
  int node = blockIdx.x * 4 + (threadIdx.x >> 6);
  int lane = threadIdx.x & 63;
  if (node >= NN) return;
  float hv = b2f(h1b[node * HID + lane]);
#pragma unroll
  for (int r = 0; r < RR; ++r) {
#pragma unroll
    for (int h = 0; h < NH; ++h) {
      float a = hv * Wgal[(r * HID + lane) * NH + h];
      float b = hv * Wgar[(r * HID + lane) * NH + h];
#pragma unroll
      for (int off = 32; off; off >>= 1) {
        a += __shfl_xor(a, off);
        b += __shfl_xor(b, off);
      }
      if (lane == 0) {
        el[((size_t)r * NN + node) * NH + h] = a;
        er[((size_t)r * NN + node) * NH + h] = b;
      }
    }
  }
}

// ======== GAT gather, ALL relations merged (unroll 2) + bg + relu -> gatb ====
__global__ void k_gatg(const int* __restrict__ offs, const int* __restrict__ degd,
                       const int* __restrict__ esrc, const u16* __restrict__ fb,
                       const float* __restrict__ el, const float* __restrict__ er,
                       const float* __restrict__ bg, u16* __restrict__ gatb) {
  int node = blockIdx.x * 4 + (threadIdx.x >> 6);
  int lane = threadIdx.x & 63;
  if (node >= NN) return;
  float o0 = 0.f, o1 = 0.f, o2 = 0.f;
#pragma unroll
  for (int r = 0; r < RR; ++r) {
    const u16* f = fb + (size_t)r * NN * NH * HID + lane;
    const float* elr = el + (size_t)r * NN * NH;
    int start = offs[r * NN + node];
    int deg = degd[r * NN + node];
    size_t eb = ((size_t)r * NN + node) * NH;
    float erv0 = er[eb], erv1 = er[eb + 1], erv2 = er[eb + 2];
    float z0 = 0.f, z1 = 0.f, z2 = 0.f;
    float a0 = 0.f, a1 = 0.f, a2 = 0.f;
    int j = 0;
    for (; j + 2 <= deg; j += 2) {
      int s0 = esrc[start + j], s1 = esrc[start + j + 1];
      const float* e0 = elr + (size_t)s0 * NH;
      const float* e1 = elr + (size_t)s1 * NH;
      const u16* p0 = f + (size_t)s0 * (NH * HID);
      const u16* p1 = f + (size_t)s1 * (NH * HID);
      float w00 = wexp(e0[0] + erv0), w01 = wexp(e0[1] + erv1), w02 = wexp(e0[2] + erv2);
      float w10 = wexp(e1[0] + erv0), w11 = wexp(e1[1] + erv1), w12 = wexp(e1[2] + erv2);
      z0 += w00 + w10; z1 += w01 + w11; z2 += w02 + w12;
      a0 += w00 * b2f(p0[0]) + w10 * b2f(p1[0]);
      a1 += w01 * b2f(p0[HID]) + w11 * b2f(p1[HID]);
      a2 += w02 * b2f(p0[2 * HID]) + w12 * b2f(p1[2 * HID]);
    }
    if (j < deg) {
      int s0 = esrc[start + j];
      const float* e0 = elr + (size_t)s0 * NH;
      const u16* p0 = f + (size_t)s0 * (NH * HID);
      float w00 = wexp(e0[0] + erv0), w01 = wexp(e0[1] + erv1), w02 = wexp(e0[2] + erv2);
      z0 += w00; z1 += w01; z2 += w02;
      a0 += w00 * b2f(p0[0]);
      a1 += w01 * b2f(p0[HID]);
      a2 += w02 * b2f(p0[2 * HID]);
    }
    o0 += a0 / (z0 + 1e-9f);
    o1 += a1 / (z1 + 1e-9f);
    o2 += a2 / (z2 + 1e-9f);
  }
  float ov[NH] = {o0, o1, o2};
#pragma unroll
  for (int h = 0; h < NH; ++h) {
    int j = h * HID + lane;
    float v = ov[h] + bg[j] + bg[NH * HID + j] + bg[2 * NH * HID + j];
    gatb[(size_t)node * (NH * HID) + j] = f2b(fmaxf(v, 0.f));
  }
}

// ======== conv2 gather, ALL relations merged (unroll 2) + b2 + sigmoid ======
__global__ void k_g2(const int* __restrict__ offs, const int* __restrict__ degd,
                     const int* __restrict__ esrc, const u16* __restrict__ fb,
                     const float* __restrict__ nd, const float* __restrict__ b2,
                     u16* __restrict__ agg2b) {
  int node = blockIdx.x * 4 + (threadIdx.x >> 6);
  int lane = threadIdx.x & 63;
  if (node >= NN) return;
  float o0 = 0.f, o1 = 0.f, o2 = 0.f;
#pragma unroll
  for (int r = 0; r < RR; ++r) {
    const u16* hw = fb + (size_t)r * NN * NH * FOUT + lane;
    int start = offs[r * NN + node];
    int deg = degd[r * NN + node];
    float a0 = 0.f, a1 = 0.f, a2 = 0.f;
    int j = 0;
    for (; j + 2 <= deg; j += 2) {
      int s0 = esrc[start + j], s1 = esrc[start + j + 1];
      const u16* p0 = hw + (size_t)s0 * (NH * FOUT);
      const u16* p1 = hw + (size_t)s1 * (NH * FOUT);
      a0 += b2f(p0[0]) + b2f(p1[0]);
      a1 += b2f(p0[FOUT]) + b2f(p1[FOUT]);
      a2 += b2f(p0[2 * FOUT]) + b2f(p1[2 * FOUT]);
    }
    if (j < deg) {
      const u16* p0 = hw + (size_t)esrc[start + j] * (NH * FOUT);
      a0 += b2f(p0[0]);
      a1 += b2f(p0[FOUT]);
      a2 += b2f(p0[2 * FOUT]);
    }
    float ndv = nd[r * NN + node];
    o0 += a0 * ndv; o1 += a1 * ndv; o2 += a2 * ndv;
  }
  float b2s = b2[lane] + b2[FOUT + lane] + b2[2 * FOUT + lane];
  float ov[NH] = {o0, o1, o2};
#pragma unroll
  for (int h = 0; h < NH; ++h) {
    float v = 1.0f / (1.0f + __expf(-(ov[h] + b2s)));
    agg2b[(size_t)node * (NH * FOUT) + h * FOUT + lane] = f2b(v);
  }
}

__global__ void k_cnt2(const int* __restrict__ gid, float* __restrict__ cnt) {
  __shared__ int loc[NB];
  if (threadIdx.x < NB) loc[threadIdx.x] = 0;
  __syncthreads();
  int i = blockIdx.x * 256 + threadIdx.x;
  if (i < NN) atomicAdd(&loc[gid[i]], 1);
  __syncthreads();
  if (threadIdx.x < NB) atomicAdd(&cnt[threadIdx.x], (float)loc[threadIdx.x]);
}

__global__ void k_pool(const u16* __restrict__ h3, const int* __restrict__ gid,
                       float* __restrict__ pooled) {
  int j = threadIdx.x;  // 0..191
  int start = blockIdx.x * 128;
  if (start >= NN) return;
  int end = start + 128;
  if (end > NN) end = NN;
  int gcur = gid[start];
  float acc = 0.f;
  for (int n = start; n < end; ++n) {
    int g = gid[n];
    if (g != gcur) {
      atomicAdd(&pooled[gcur * (NH * FOUT) + j], acc);
      acc = 0.f;
      gcur = g;
    }
    acc += b2f(h3[(size_t)n * (NH * FOUT) + j]);
  }
  atomicAdd(&pooled[gcur * (NH * FOUT) + j], acc);
}

__global__ void k_final(const float* __restrict__ pooled, const float* __restrict__ cnt,
                        const float* __restrict__ Wc, const float* __restrict__ bc,
                        float* __restrict__ out) {
  int t = threadIdx.x;
  if (t >= NB * NH) return;
  int b = t / NH;
  float inv = 1.0f / fmaxf(cnt[b], 1.0f);
  const float* p = pooled + t * FOUT;
  float sacc = 0.f;
  for (int c = 0; c < NC; ++c) {
    float acc = bc[c];
    for (int o = 0; o < FOUT; ++o) acc += p[o] * inv * Wc[o * NC + c];
    sacc += 1.0f / (1.0f + __expf(-acc));
  }
  out[t] = sacc * (1.0f / NC);
}

extern "C" void kernel_launch(void* const* d_in, const int* in_sizes, int n_in,
                              void* d_out, int out_size, void* d_ws, size_t ws_size,
                              hipStream_t stream) {
  const float* x = (const float*)d_in[0];
  const int* src = (const int*)d_in[1];
  const int* dst = (const int*)d_in[2];
  const int* gid = (const int*)d_in[3];
  const float* W1 = (const float*)d_in[4];
  const float* b1 = (const float*)d_in[5];
  const float* Wg = (const float*)d_in[6];
  const float* al = (const float*)d_in[7];
  const float* ar = (const float*)d_in[8];
  const float* bg = (const float*)d_in[9];
  const float* W2 = (const float*)d_in[10];
  const float* b2 = (const float*)d_in[11];
  const float* Wc = (const float*)d_in[12];
  const float* bc = (const float*)d_in[13];
  float* out = (float*)d_out;

  // ---- workspace layout (~127 MB; 144 MB proven available in R2) ----
  int* degs = (int*)d_ws;                          // 150000
  int* degd = degs + RR * NN;                      // 150000
  float* cnt = (float*)(degd + RR * NN);           // 8
  float* pooled = cnt + NB;                        // 1536
  size_t zero_bytes = ((size_t)2 * RR * NN + NB + NB * NH * FOUT) * 4;
  int* offs = (int*)(pooled + NB * NH * FOUT);     // 150008
  int* cursor = offs + RR * NN + 8;                // 150000
  int* bsum = cursor + RR * NN;                    // 1024
  int* esrc = bsum + 1024;                         // 1200000
  float* ns = (float*)(esrc + (size_t)RR * EE);    // 150000
  float* nd = ns + RR * NN;                        // 150000
  float* el = nd + RR * NN;                        // 450000
  float* er = el + (size_t)RR * NN * NH;           // 450000
  float* Wgal = er + (size_t)RR * NN * NH;         // 576
  float* Wgar = Wgal + RR * HID * NH;              // 576
  u16* xb = (u16*)(Wgar + RR * HID * NH);          // 6.4M u16
  u16* h1b = xb + (size_t)NN * FIN;                // 3.2M
  u16* fb = h1b + (size_t)NN * HID;                // 3 x 9.6M (f0|f1|f2 contiguous)
  u16* gatb = fb + (size_t)RR * NN * NH * HID;     // 9.6M
  u16* agg2b = gatb + (size_t)NN * NH * HID;       // 9.6M

  hipMemsetAsync(d_ws, 0, zero_bytes, stream);

  const int nscan = RR * NN;
  const int nblk1 = (nscan + 255) / 256;

  // degrees + norms + CSR build
  k_deg<<<(RR * EE + 255) / 256, 256, 0, stream>>>(src, dst, degs, degd);
  k_norm<<<(nscan + 255) / 256, 256, 0, stream>>>(degs, degd, ns, nd);
  k_scan1<<<nblk1, 256, 0, stream>>>(degd, offs, bsum);
  k_scan2<<<1, 1024, 0, stream>>>(bsum, nblk1);
  k_scan3<<<nblk1, 256, 0, stream>>>(offs, bsum, cursor);
  k_fill<<<(RR * EE + 255) / 256, 256, 0, stream>>>(src, dst, cursor, esrc);

  // casts + tiny precompute
  k_cast<<<(NN * FIN / 4 + 255) / 256, 256, 0, stream>>>((const float4*)x, (u16x4*)xb,
                                                         NN * FIN / 4);
  k_wgal<<<1, 576, 0, stream>>>(Wg, al, ar, Wgal, Wgar);

  // conv1: MFMA GEMM (grid.y=relation; staging in fb) + gather+bias+L2norm
  k_gemm<FIN, HID, 1><<<dim3(782, RR), 256, 0, stream>>>(
      xb, W1, FIN * HID, fb, (long)NN * HID, ns, NN, NN);
  k_g1<<<(NN + 3) / 4, 256, 0, stream>>>(offs, degd, esrc, fb, nd, b1, h1b);

  // el/er for all relations
  k_eler<<<(NN + 3) / 4, 256, 0, stream>>>(h1b, Wgal, Wgar, el, er);

  // GAT: one GEMM dispatch for all relations -> f0,f1,f2; one merged gather
  k_gemm<HID, NH * HID, 0><<<dim3(782, RR), 256, 0, stream>>>(
      h1b, Wg, HID * NH * HID, fb, (long)NN * NH * HID, ns, 0, NN);
  k_gatg<<<(NN + 3) / 4, 256, 0, stream>>>(offs, degd, esrc, fb, el, er, bg, gatb);

  // conv2: one GEMM dispatch (rows = n*NH+h) -> f0,f1,f2; one merged gather
  k_gemm<HID, FOUT, 2><<<dim3(2344, RR), 256, 0, stream>>>(
      gatb, W2, HID * FOUT, fb, (long)NN * NH * FOUT, ns, NN, NN * NH);
  k_g2<<<(NN + 3) / 4, 256, 0, stream>>>(offs, degd, esrc, fb, nd, b2, agg2b);

  // pooling + classifier
  k_cnt2<<<(NN + 255) / 256, 256, 0, stream>>>(gid, cnt);
  k_pool<<<(NN + 127) / 128, 192, 0, stream>>>(agg2b, gid, pooled);
  k_final<<<1, 64, 0, stream>>>(pooled, cnt, Wc, bc, out);
}

// Round 8
// 686.151 us; speedup vs baseline: 3.1759x; 1.1038x over previous
//
#include <hip/hip_runtime.h>
#include <math.h>

#define NN 50000
#define EE 400000
#define RR 3
#define NH 3
#define FIN 128
#define HID 64
#define FOUT 64
#define NC 16
#define NB 8
#define NGAT 208  // 192 f cols + 6 el/er cols + 10 pad

typedef __attribute__((ext_vector_type(8))) short v8s;  // 8 bf16 (4 VGPRs)
typedef __attribute__((ext_vector_type(4))) float v4f;  // MFMA acc
typedef unsigned short u16;
typedef __attribute__((ext_vector_type(4))) unsigned short u16x4;

__device__ __forceinline__ u16 f2b(float f) {  // f32 -> bf16 RNE
  unsigned u = __float_as_uint(f);
  return (u16)((u + 0x7fffu + ((u >> 16) & 1u)) >> 16);
}
__device__ __forceinline__ float b2f(u16 b) {
  return __uint_as_float(((unsigned)b) << 16);
}
__device__ __forceinline__ float wexp(float e) {  // leaky_relu(0.2) then exp
  e = e > 0.f ? e : 0.2f * e;
  return __expf(e);
}

// ======== degree histogram ========
__global__ void k_deg(const int* __restrict__ src, const int* __restrict__ dst,
                      int* __restrict__ degs, int* __restrict__ degd) {
  int i = blockIdx.x * 256 + threadIdx.x;
  if (i >= RR * EE) return;
  int r = i / EE;
  atomicAdd(&degs[r * NN + src[i]], 1);
  atomicAdd(&degd[r * NN + dst[i]], 1);
}

__global__ void k_norm(const int* __restrict__ degs, const int* __restrict__ degd,
                       float* __restrict__ ns, float* __restrict__ nd) {
  int i = blockIdx.x * 256 + threadIdx.x;
  if (i >= RR * NN) return;
  ns[i] = 1.0f / sqrtf((float)(degs[i] > 1 ? degs[i] : 1));
  nd[i] = 1.0f / sqrtf((float)(degd[i] > 1 ? degd[i] : 1));
}

// ======== exclusive scan (3 kernels) ========
__global__ void k_scan1(const int* __restrict__ deg, int* __restrict__ offs,
                        int* __restrict__ bsum) {
  __shared__ int sh[256];
  int gid = blockIdx.x * 256 + threadIdx.x;
  int v = (gid < RR * NN) ? deg[gid] : 0;
  sh[threadIdx.x] = v;
  __syncthreads();
  for (int off = 1; off < 256; off <<= 1) {
    int t = (threadIdx.x >= off) ? sh[threadIdx.x - off] : 0;
    __syncthreads();
    sh[threadIdx.x] += t;
    __syncthreads();
  }
  if (gid < RR * NN) offs[gid] = sh[threadIdx.x] - v;
  if (threadIdx.x == 255) bsum[blockIdx.x] = sh[255];
}

__global__ void k_scan2(int* __restrict__ bsum, int nb) {
  __shared__ int sh[1024];
  int v = (threadIdx.x < nb) ? bsum[threadIdx.x] : 0;
  sh[threadIdx.x] = v;
  __syncthreads();
  for (int off = 1; off < 1024; off <<= 1) {
    int t = (threadIdx.x >= off) ? sh[threadIdx.x - off] : 0;
    __syncthreads();
    sh[threadIdx.x] += t;
    __syncthreads();
  }
  if (threadIdx.x < nb) bsum[threadIdx.x] = sh[threadIdx.x] - v;
}

__global__ void k_scan3(int* __restrict__ offs, const int* __restrict__ bsum,
                        int* __restrict__ cursor) {
  int i = blockIdx.x * 256 + threadIdx.x;
  if (i >= RR * NN) return;
  int v = offs[i] + bsum[i / 256];
  offs[i] = v;
  cursor[i] = v;
}

// bucket edges by destination; also record dst per position
__global__ void k_fill(const int* __restrict__ src, const int* __restrict__ dst,
                       int* __restrict__ cursor, int* __restrict__ esrc,
                       int* __restrict__ edst) {
  int i = blockIdx.x * 256 + threadIdx.x;
  if (i >= RR * EE) return;
  int r = i / EE;
  int d = dst[i];
  int pos = atomicAdd(&cursor[r * NN + d], 1);
  esrc[pos] = src[i];
  edst[pos] = d;
}

// ======== f32 -> bf16 cast ========
__global__ void k_cast(const float4* __restrict__ in, u16x4* __restrict__ out, int n4) {
  int i = blockIdx.x * 256 + threadIdx.x;
  if (i >= n4) return;
  float4 v = in[i];
  u16x4 o;
  o.x = f2b(v.x); o.y = f2b(v.y); o.z = f2b(v.z); o.w = f2b(v.w);
  out[i] = o;
}

// ======== Bcomp: [r][k][208] = [Wg | Wg.al (3) | Wg.ar (3) | 0 pad] ========
__global__ void k_bcomp(const float* __restrict__ Wg, const float* __restrict__ al,
                        const float* __restrict__ ar, float* __restrict__ B) {
  int i = blockIdx.x * 256 + threadIdx.x;
  if (i >= RR * HID * NGAT) return;
  int col = i % NGAT;
  int k = (i / NGAT) % HID;
  int r = i / (NGAT * HID);
  float v = 0.f;
  if (col < NH * HID) {
    v = Wg[((size_t)(r * HID + k)) * (NH * HID) + col];
  } else if (col < NH * HID + 6) {
    int c2 = col - NH * HID;
    int isar = c2 / NH, h = c2 % NH;
    const float* wg = Wg + ((size_t)(r * HID + k)) * (NH * HID) + h * HID;
    const float* av = (isar ? ar : al) + (r * NH + h) * HID;
    float a = 0.f;
#pragma unroll 8
    for (int c = 0; c < HID; ++c) a += wg[c] * av[c];
    v = a;
  }
  B[i] = v;
}

// ======== MFMA GEMM (verified mapping from R5) ========
template <int K, int N, int SCALE_MODE>
__global__ __launch_bounds__(256) void k_gemm(const u16* __restrict__ A,
                                              const float* __restrict__ B0, int bstr,
                                              u16* __restrict__ C0, long cstr,
                                              const float* __restrict__ s0, int sstr,
                                              int M) {
  constexpr int KP = K + 8;
  __shared__ __align__(16) u16 Bt[N * KP];
  const float* B = B0 + (size_t)blockIdx.y * bstr;
  u16* C = C0 + (size_t)blockIdx.y * cstr;
  const float* scale = s0 + (size_t)blockIdx.y * sstr;
  for (int i = threadIdx.x; i < K * N; i += 256) {
    int k = i / N, n = i % N;
    Bt[n * KP + k] = f2b(B[(size_t)k * N + n]);
  }
  __syncthreads();
  int wid = threadIdx.x >> 6, lane = threadIdx.x & 63;
  int l15 = lane & 15, lg = lane >> 4;
  constexpr int NT = N / 16;
  int ntiles = (M + 63) >> 6;
  for (int tile = blockIdx.x; tile < ntiles; tile += gridDim.x) {
    int mbase = tile * 64 + wid * 16;
    v4f acc[NT];
#pragma unroll
    for (int t = 0; t < NT; ++t) acc[t] = (v4f)(0.f);
    int arow = mbase + l15;
    if (arow >= M) arow = M - 1;
    const u16* ap = A + (size_t)arow * K + lg * 8;
#pragma unroll
    for (int ks = 0; ks < K / 32; ++ks) {
      v8s a = *(const v8s*)(ap + ks * 32);
#pragma unroll
      for (int t = 0; t < NT; ++t) {
        v8s b = *(const v8s*)(&Bt[(t * 16 + l15) * KP + lg * 8 + ks * 32]);
        acc[t] = __builtin_amdgcn_mfma_f32_16x16x32_bf16(a, b, acc[t], 0, 0, 0);
      }
    }
#pragma unroll
    for (int q = 0; q < 4; ++q) {
      int row = mbase + lg * 4 + q;
      if (row < M) {
        float s = 1.f;
        if (SCALE_MODE == 1) s = scale[row];
        if (SCALE_MODE == 2) s = scale[row / NH];
#pragma unroll
        for (int t = 0; t < NT; ++t)
          C[(size_t)row * N + t * 16 + l15] = f2b(acc[t][q] * s);
      }
    }
  }
}

// ======== conv1 gather (unroll 4) + bias + L2 normalize -> h1b ========
__global__ void k_g1(const int* __restrict__ offs, const int* __restrict__ degd,
                     const int* __restrict__ esrc, const u16* __restrict__ hw,
                     const float* __restrict__ nd, const float* __restrict__ b1,
                     u16* __restrict__ h1b) {
  int node = blockIdx.x * 4 + (threadIdx.x >> 6);
  int lane = threadIdx.x & 63;
  if (node >= NN) return;
  float v = 0.f;
#pragma unroll
  for (int r = 0; r < RR; ++r) {
    int start = offs[r * NN + node];
    int deg = degd[r * NN + node];
    const u16* base = hw + (size_t)r * NN * HID + lane;
    float t = 0.f;
    int j = 0;
    for (; j + 4 <= deg; j += 4) {
      int s0 = esrc[start + j], s1 = esrc[start + j + 1];
      int s2 = esrc[start + j + 2], s3 = esrc[start + j + 3];
      float a0 = b2f(base[(size_t)s0 * HID]);
      float a1 = b2f(base[(size_t)s1 * HID]);
      float a2 = b2f(base[(size_t)s2 * HID]);
      float a3 = b2f(base[(size_t)s3 * HID]);
      t += (a0 + a1) + (a2 + a3);
    }
    for (; j < deg; ++j) t += b2f(base[(size_t)esrc[start + j] * HID]);
    v += t * nd[r * NN + node];
  }
  v += b1[lane] + b1[HID + lane] + b1[2 * HID + lane];
  float sq = v * v;
  for (int off = 32; off; off >>= 1) sq += __shfl_xor(sq, off);
  float nrm = sqrtf(sq);
  nrm = nrm > 1e-12f ? nrm : 1e-12f;
  h1b[node * HID + lane] = f2b(v / nrm);
}

// ======== extract el/er cols from fb rows into compact table ========
// elr[(r*NN+n)*8 + {0..2}] = el_h ; + {4..6} = er_h
__global__ void k_elx(const u16* __restrict__ fb, u16* __restrict__ elr) {
  int i = blockIdx.x * 256 + threadIdx.x;
  if (i >= RR * NN) return;
  const u16* row = fb + (size_t)i * NGAT + NH * HID;
  u16x4 a, b;
  a.x = row[0]; a.y = row[1]; a.z = row[2]; a.w = 0;
  b.x = row[3]; b.y = row[4]; b.z = row[5]; b.w = 0;
  *(u16x4*)(elr + (size_t)i * 8) = a;
  *(u16x4*)(elr + (size_t)i * 8 + 4) = b;
}

// ======== per-edge softmax weights (computed ONCE per edge, not per lane) ====
__global__ void k_ew(const int* __restrict__ esrc, const int* __restrict__ edst,
                     const u16* __restrict__ elr, u16* __restrict__ ew) {
  int i = blockIdx.x * 256 + threadIdx.x;
  if (i >= RR * EE) return;
  int r = i / EE;
  int s = esrc[i], d = edst[i];
  const u16* es = elr + ((size_t)(r * NN + s)) * 8;      // el of src
  const u16* ed = elr + ((size_t)(r * NN + d)) * 8 + 4;  // er of dst
  u16x4 o;
  o.x = f2b(wexp(b2f(es[0]) + b2f(ed[0])));
  o.y = f2b(wexp(b2f(es[1]) + b2f(ed[1])));
  o.z = f2b(wexp(b2f(es[2]) + b2f(ed[2])));
  o.w = 0;
  *(u16x4*)(ew + (size_t)i * 4) = o;
}

// ======== GAT gather: precomputed weights, unroll 4, + bg + relu -> gatb =====
__global__ void k_gatg(const int* __restrict__ offs, const int* __restrict__ degd,
                       const int* __restrict__ esrc, const u16* __restrict__ fb,
                       const u16* __restrict__ ew, const float* __restrict__ bg,
                       u16* __restrict__ gatb) {
  int node = blockIdx.x * 4 + (threadIdx.x >> 6);
  int lane = threadIdx.x & 63;
  if (node >= NN) return;
  float o0 = 0.f, o1 = 0.f, o2 = 0.f;
#pragma unroll
  for (int r = 0; r < RR; ++r) {
    const u16* f = fb + (size_t)r * NN * NGAT + lane;
    int start = offs[r * NN + node];
    int deg = degd[r * NN + node];
    float z0 = 0.f, z1 = 0.f, z2 = 0.f;
    float a0 = 0.f, a1 = 0.f, a2 = 0.f;
    int j = 0;
    for (; j + 4 <= deg; j += 4) {
      int p = start + j;
      int s0 = esrc[p], s1 = esrc[p + 1], s2 = esrc[p + 2], s3 = esrc[p + 3];
      u16x4 wa = *(const u16x4*)(ew + (size_t)p * 4);
      u16x4 wb = *(const u16x4*)(ew + (size_t)(p + 1) * 4);
      u16x4 wc = *(const u16x4*)(ew + (size_t)(p + 2) * 4);
      u16x4 wd = *(const u16x4*)(ew + (size_t)(p + 3) * 4);
      const u16* q0 = f + (size_t)s0 * NGAT;
      const u16* q1 = f + (size_t)s1 * NGAT;
      const u16* q2 = f + (size_t)s2 * NGAT;
      const u16* q3 = f + (size_t)s3 * NGAT;
      float w;
      w = b2f(wa.x); z0 += w; a0 += w * b2f(q0[0]);
      w = b2f(wa.y); z1 += w; a1 += w * b2f(q0[HID]);
      w = b2f(wa.z); z2 += w; a2 += w * b2f(q0[2 * HID]);
      w = b2f(wb.x); z0 += w; a0 += w * b2f(q1[0]);
      w = b2f(wb.y); z1 += w; a1 += w * b2f(q1[HID]);
      w = b2f(wb.z); z2 += w; a2 += w * b2f(q1[2 * HID]);
      w = b2f(wc.x); z0 += w; a0 += w * b2f(q2[0]);
      w = b2f(wc.y); z1 += w; a1 += w * b2f(q2[HID]);
      w = b2f(wc.z); z2 += w; a2 += w * b2f(q2[2 * HID]);
      w = b2f(wd.x); z0 += w; a0 += w * b2f(q3[0]);
      w = b2f(wd.y); z1 += w; a1 += w * b2f(q3[HID]);
      w = b2f(wd.z); z2 += w; a2 += w * b2f(q3[2 * HID]);
    }
    for (; j < deg; ++j) {
      int p = start + j;
      int s0 = esrc[p];
      u16x4 wa = *(const u16x4*)(ew + (size_t)p * 4);
      const u16* q0 = f + (size_t)s0 * NGAT;
      float w;
      w = b2f(wa.x); z0 += w; a0 += w * b2f(q0[0]);
      w = b2f(wa.y); z1 += w; a1 += w * b2f(q0[HID]);
      w = b2f(wa.z); z2 += w; a2 += w * b2f(q0[2 * HID]);
    }
    o0 += a0 / (z0 + 1e-9f);
    o1 += a1 / (z1 + 1e-9f);
    o2 += a2 / (z2 + 1e-9f);
  }
  float ov[NH] = {o0, o1, o2};
#pragma unroll
  for (int h = 0; h < NH; ++h) {
    int j = h * HID + lane;
    float v = ov[h] + bg[j] + bg[NH * HID + j] + bg[2 * NH * HID + j];
    gatb[(size_t)node * (NH * HID) + j] = f2b(fmaxf(v, 0.f));
  }
}

// ======== conv2 gather, unroll 4, + b2 + sigmoid -> agg2b ========
__global__ void k_g2(const int* __restrict__ offs, const int* __restrict__ degd,
                     const int* __restrict__ esrc, const u16* __restrict__ fb,
                     const float* __restrict__ nd, const float* __restrict__ b2,
                     u16* __restrict__ agg2b) {
  int node = blockIdx.x * 4 + (threadIdx.x >> 6);
  int lane = threadIdx.x & 63;
  if (node >= NN) return;
  float o0 = 0.f, o1 = 0.f, o2 = 0.f;
#pragma unroll
  for (int r = 0; r < RR; ++r) {
    const u16* hw = fb + (size_t)r * NN * NH * FOUT + lane;
    int start = offs[r * NN + node];
    int deg = degd[r * NN + node];
    float a0 = 0.f, a1 = 0.f, a2 = 0.f;
    int j = 0;
    for (; j + 4 <= deg; j += 4) {
      int p = start + j;
      const u16* q0 = hw + (size_t)esrc[p] * (NH * FOUT);
      const u16* q1 = hw + (size_t)esrc[p + 1] * (NH * FOUT);
      const u16* q2 = hw + (size_t)esrc[p + 2] * (NH * FOUT);
      const u16* q3 = hw + (size_t)esrc[p + 3] * (NH * FOUT);
      a0 += (b2f(q0[0]) + b2f(q1[0])) + (b2f(q2[0]) + b2f(q3[0]));
      a1 += (b2f(q0[FOUT]) + b2f(q1[FOUT])) + (b2f(q2[FOUT]) + b2f(q3[FOUT]));
      a2 += (b2f(q0[2 * FOUT]) + b2f(q1[2 * FOUT])) +
            (b2f(q2[2 * FOUT]) + b2f(q3[2 * FOUT]));
    }
    for (; j < deg; ++j) {
      const u16* q0 = hw + (size_t)esrc[start + j] * (NH * FOUT);
      a0 += b2f(q0[0]);
      a1 += b2f(q0[FOUT]);
      a2 += b2f(q0[2 * FOUT]);
    }
    float ndv = nd[r * NN + node];
    o0 += a0 * ndv; o1 += a1 * ndv; o2 += a2 * ndv;
  }
  float b2s = b2[lane] + b2[FOUT + lane] + b2[2 * FOUT + lane];
  float ov[NH] = {o0, o1, o2};
#pragma unroll
  for (int h = 0; h < NH; ++h) {
    float v = 1.0f / (1.0f + __expf(-(ov[h] + b2s)));
    agg2b[(size_t)node * (NH * FOUT) + h * FOUT + lane] = f2b(v);
  }
}

__global__ void k_cnt2(const int* __restrict__ gid, float* __restrict__ cnt) {
  __shared__ int loc[NB];
  if (threadIdx.x < NB) loc[threadIdx.x] = 0;
  __syncthreads();
  int i = blockIdx.x * 256 + threadIdx.x;
  if (i < NN) atomicAdd(&loc[gid[i]], 1);
  __syncthreads();
  if (threadIdx.x < NB) atomicAdd(&cnt[threadIdx.x], (float)loc[threadIdx.x]);
}

__global__ void k_pool(const u16* __restrict__ h3, const int* __restrict__ gid,
                       float* __restrict__ pooled) {
  int j = threadIdx.x;  // 0..191
  int start = blockIdx.x * 128;
  if (start >= NN) return;
  int end = start + 128;
  if (end > NN) end = NN;
  int gcur = gid[start];
  float acc = 0.f;
  for (int n = start; n < end; ++n) {
    int g = gid[n];
    if (g != gcur) {
      atomicAdd(&pooled[gcur * (NH * FOUT) + j], acc);
      acc = 0.f;
      gcur = g;
    }
    acc += b2f(h3[(size_t)n * (NH * FOUT) + j]);
  }
  atomicAdd(&pooled[gcur * (NH * FOUT) + j], acc);
}

__global__ void k_final(const float* __restrict__ pooled, const float* __restrict__ cnt,
                        const float* __restrict__ Wc, const float* __restrict__ bc,
                        float* __restrict__ out) {
  int t = threadIdx.x;
  if (t >= NB * NH) return;
  int b = t / NH;
  float inv = 1.0f / fmaxf(cnt[b], 1.0f);
  const float* p = pooled + t * FOUT;
  float sacc = 0.f;
  for (int c = 0; c < NC; ++c) {
    float acc = bc[c];
    for (int o = 0; o < FOUT; ++o) acc += p[o] * inv * Wc[o * NC + c];
    sacc += 1.0f / (1.0f + __expf(-acc));
  }
  out[t] = sacc * (1.0f / NC);
}

extern "C" void kernel_launch(void* const* d_in, const int* in_sizes, int n_in,
                              void* d_out, int out_size, void* d_ws, size_t ws_size,
                              hipStream_t stream) {
  const float* x = (const float*)d_in[0];
  const int* src = (const int*)d_in[1];
  const int* dst = (const int*)d_in[2];
  const int* gid = (const int*)d_in[3];
  const float* W1 = (const float*)d_in[4];
  const float* b1 = (const float*)d_in[5];
  const float* Wg = (const float*)d_in[6];
  const float* al = (const float*)d_in[7];
  const float* ar = (const float*)d_in[8];
  const float* bg = (const float*)d_in[9];
  const float* W2 = (const float*)d_in[10];
  const float* b2 = (const float*)d_in[11];
  const float* Wc = (const float*)d_in[12];
  const float* bc = (const float*)d_in[13];
  float* out = (float*)d_out;

  // ---- workspace layout (~126 MB; 127 MB proven in R7) ----
  int* degs = (int*)d_ws;                         // 150000
  int* degd = degs + RR * NN;                     // 150000
  float* cnt = (float*)(degd + RR * NN);          // 8
  float* pooled = cnt + NB;                       // 1536
  size_t zero_bytes = ((size_t)2 * RR * NN + NB + NB * NH * FOUT) * 4;
  int* offs = (int*)(pooled + NB * NH * FOUT);    // 150008
  int* cursor = offs + RR * NN + 8;               // 150000
  int* bsum = cursor + RR * NN;                   // 1024
  int* esrc = bsum + 1024;                        // 1200000
  int* edst = esrc + (size_t)RR * EE;             // 1200000
  float* ns = (float*)(edst + (size_t)RR * EE);   // 150000
  float* nd = ns + RR * NN;                       // 150000
  float* Bcomp = nd + RR * NN;                    // RR*64*208 = 39936
  u16* elr = (u16*)(Bcomp + RR * HID * NGAT);     // RR*NN*8    = 1.2M u16
  u16* ew = elr + (size_t)RR * NN * 8;            // RR*EE*4    = 4.8M u16
  u16* xb = ew + (size_t)RR * EE * 4;             // NN*FIN     = 6.4M u16
  u16* h1b = xb + (size_t)NN * FIN;               // NN*HID     = 3.2M u16
  u16* fb = h1b + (size_t)NN * HID;               // RR*NN*208  = 31.2M u16
  u16* gatb = fb + (size_t)RR * NN * NGAT;        // NN*NH*HID  = 9.6M u16
  u16* agg2b = xb;  // alias: xb+h1b (19.2MB) dead before k_g2 writes agg2b

  hipMemsetAsync(d_ws, 0, zero_bytes, stream);

  const int nscan = RR * NN;
  const int nblk1 = (nscan + 255) / 256;

  // degrees + norms + CSR build (with edst)
  k_deg<<<(RR * EE + 255) / 256, 256, 0, stream>>>(src, dst, degs, degd);
  k_norm<<<(nscan + 255) / 256, 256, 0, stream>>>(degs, degd, ns, nd);
  k_scan1<<<nblk1, 256, 0, stream>>>(degd, offs, bsum);
  k_scan2<<<1, 1024, 0, stream>>>(bsum, nblk1);
  k_scan3<<<nblk1, 256, 0, stream>>>(offs, bsum, cursor);
  k_fill<<<(RR * EE + 255) / 256, 256, 0, stream>>>(src, dst, cursor, esrc, edst);

  // casts + composite-B build
  k_cast<<<(NN * FIN / 4 + 255) / 256, 256, 0, stream>>>((const float4*)x, (u16x4*)xb,
                                                         NN * FIN / 4);
  k_bcomp<<<(RR * HID * NGAT + 255) / 256, 256, 0, stream>>>(Wg, al, ar, Bcomp);

  // conv1: MFMA GEMM (grid.y=relation; stride-64 rows in fb) + gather+norm
  k_gemm<FIN, HID, 1><<<dim3(782, RR), 256, 0, stream>>>(
      xb, W1, FIN * HID, fb, (long)NN * HID, ns, NN, NN);
  k_g1<<<(NN + 3) / 4, 256, 0, stream>>>(offs, degd, esrc, fb, nd, b1, h1b);

  // GAT: one GEMM (N=208, f cols + el/er cols) -> fb; extract; edge weights
  k_gemm<HID, NGAT, 0><<<dim3(782, RR), 256, 0, stream>>>(
      h1b, Bcomp, HID * NGAT, fb, (long)NN * NGAT, ns, 0, NN);
  k_elx<<<(nscan + 255) / 256, 256, 0, stream>>>(fb, elr);
  k_ew<<<(RR * EE + 255) / 256, 256, 0, stream>>>(esrc, edst, elr, ew);
  k_gatg<<<(NN + 3) / 4, 256, 0, stream>>>(offs, degd, esrc, fb, ew, bg, gatb);

  // conv2: one GEMM (rows = n*NH+h, stride-192 rows in fb) + merged gather
  k_gemm<HID, FOUT, 2><<<dim3(2344, RR), 256, 0, stream>>>(
      gatb, W2, HID * FOUT, fb, (long)NN * NH * FOUT, ns, NN, NN * NH);
  k_g2<<<(NN + 3) / 4, 256, 0, stream>>>(offs, degd, esrc, fb, nd, b2, agg2b);

  // pooling + classifier
  k_cnt2<<<(NN + 255) / 256, 256, 0, stream>>>(gid, cnt);
  k_pool<<<(NN + 127) / 128, 192, 0, stream>>>(agg2b, gid, pooled);
  k_final<<<1, 64, 0, stream>>>(pooled, cnt, Wc, bc, out);
}

// Round 9
// 666.931 us; speedup vs baseline: 3.2674x; 1.0288x over previous
//
#include <hip/hip_runtime.h>
#include <math.h>

#define NN 50000
#define EE 400000
#define RR 3
#define NH 3
#define FIN 128
#define HID 64
#define FOUT 64
#define NC 16
#define NB 8
#define NGAT 208  // 192 f cols + 6 el/er cols + 10 pad

typedef __attribute__((ext_vector_type(8))) short v8s;  // 8 bf16 (4 VGPRs)
typedef __attribute__((ext_vector_type(4))) float v4f;  // MFMA acc
typedef unsigned short u16;
typedef unsigned char u8;
typedef unsigned int u32;
typedef __attribute__((ext_vector_type(4))) unsigned short u16x4;

#define QS 32.0f    // fp8 pre-scale
#define IQS (1.0f / 32.0f)

__device__ __forceinline__ u16 f2b(float f) {  // f32 -> bf16 RNE
  unsigned u = __float_as_uint(f);
  return (u16)((u + 0x7fffu + ((u >> 16) & 1u)) >> 16);
}
__device__ __forceinline__ float b2f(u16 b) {
  return __uint_as_float(((unsigned)b) << 16);
}
__device__ __forceinline__ float wexp(float e) {  // leaky_relu(0.2) then exp
  e = e > 0.f ? e : 0.2f * e;
  return __expf(e);
}
__device__ __forceinline__ u8 f2e(float v) {  // f32 -> fp8 (HW)
  return (u8)(__builtin_amdgcn_cvt_pk_fp8_f32(v, 0.f, 0, false) & 0xff);
}

// ======== degree histogram ========
__global__ void k_deg(const int* __restrict__ src, const int* __restrict__ dst,
                      int* __restrict__ degs, int* __restrict__ degd) {
  int i = blockIdx.x * 256 + threadIdx.x;
  if (i >= RR * EE) return;
  int r = i / EE;
  atomicAdd(&degs[r * NN + src[i]], 1);
  atomicAdd(&degd[r * NN + dst[i]], 1);
}

__global__ void k_norm(const int* __restrict__ degs, const int* __restrict__ degd,
                       float* __restrict__ ns, float* __restrict__ nd) {
  int i = blockIdx.x * 256 + threadIdx.x;
  if (i >= RR * NN) return;
  ns[i] = 1.0f / sqrtf((float)(degs[i] > 1 ? degs[i] : 1));
  nd[i] = 1.0f / sqrtf((float)(degd[i] > 1 ? degd[i] : 1));
}

// ======== exclusive scan (3 kernels) ========
__global__ void k_scan1(const int* __restrict__ deg, int* __restrict__ offs,
                        int* __restrict__ bsum) {
  __shared__ int sh[256];
  int gid = blockIdx.x * 256 + threadIdx.x;
  int v = (gid < RR * NN) ? deg[gid] : 0;
  sh[threadIdx.x] = v;
  __syncthreads();
  for (int off = 1; off < 256; off <<= 1) {
    int t = (threadIdx.x >= off) ? sh[threadIdx.x - off] : 0;
    __syncthreads();
    sh[threadIdx.x] += t;
    __syncthreads();
  }
  if (gid < RR * NN) offs[gid] = sh[threadIdx.x] - v;
  if (threadIdx.x == 255) bsum[blockIdx.x] = sh[255];
}

__global__ void k_scan2(int* __restrict__ bsum, int nb) {
  __shared__ int sh[1024];
  int v = (threadIdx.x < nb) ? bsum[threadIdx.x] : 0;
  sh[threadIdx.x] = v;
  __syncthreads();
  for (int off = 1; off < 1024; off <<= 1) {
    int t = (threadIdx.x >= off) ? sh[threadIdx.x - off] : 0;
    __syncthreads();
    sh[threadIdx.x] += t;
    __syncthreads();
  }
  if (threadIdx.x < nb) bsum[threadIdx.x] = sh[threadIdx.x] - v;
}

__global__ void k_scan3(int* __restrict__ offs, const int* __restrict__ bsum,
                        int* __restrict__ cursor) {
  int i = blockIdx.x * 256 + threadIdx.x;
  if (i >= RR * NN) return;
  int v = offs[i] + bsum[i / 256];
  offs[i] = v;
  cursor[i] = v;
}

// bucket edges by destination; also record dst per position
__global__ void k_fill(const int* __restrict__ src, const int* __restrict__ dst,
                       int* __restrict__ cursor, int* __restrict__ esrc,
                       int* __restrict__ edst) {
  int i = blockIdx.x * 256 + threadIdx.x;
  if (i >= RR * EE) return;
  int r = i / EE;
  int d = dst[i];
  int pos = atomicAdd(&cursor[r * NN + d], 1);
  esrc[pos] = src[i];
  edst[pos] = d;
}

// ======== f32 -> bf16 cast ========
__global__ void k_cast(const float4* __restrict__ in, u16x4* __restrict__ out, int n4) {
  int i = blockIdx.x * 256 + threadIdx.x;
  if (i >= n4) return;
  float4 v = in[i];
  u16x4 o;
  o.x = f2b(v.x); o.y = f2b(v.y); o.z = f2b(v.z); o.w = f2b(v.w);
  out[i] = o;
}

// ======== Bcomp: [r][k][208] = [Wg | Wg.al (3) | Wg.ar (3) | 0 pad] ========
__global__ void k_bcomp(const float* __restrict__ Wg, const float* __restrict__ al,
                        const float* __restrict__ ar, float* __restrict__ B) {
  int i = blockIdx.x * 256 + threadIdx.x;
  if (i >= RR * HID * NGAT) return;
  int col = i % NGAT;
  int k = (i / NGAT) % HID;
  int r = i / (NGAT * HID);
  float v = 0.f;
  if (col < NH * HID) {
    v = Wg[((size_t)(r * HID + k)) * (NH * HID) + col];
  } else if (col < NH * HID + 6) {
    int c2 = col - NH * HID;
    int isar = c2 / NH, h = c2 % NH;
    const float* wg = Wg + ((size_t)(r * HID + k)) * (NH * HID) + h * HID;
    const float* av = (isar ? ar : al) + (r * NH + h) * HID;
    float a = 0.f;
#pragma unroll 8
    for (int c = 0; c < HID; ++c) a += wg[c] * av[c];
    v = a;
  }
  B[i] = v;
}

// ======== MFMA GEMM with fp8-pack epilogues ========
// OUTMODE 1: conv1 -> u8 C[(y*M+row)*64+col] = fp8(acc*scale[row]*QS)
// OUTMODE 2: GAT   -> u32 C[(y*M+row)*64+c64] bytes=heads (fp8*QS); tile12 -> elr bf16
// OUTMODE 3: conv2 -> u8 at ((r*M+row)*64+col)*4+head, fp8(acc*scale[row]*QS)
template <int K, int N, int OUTMODE>
__global__ __launch_bounds__(256) void k_gemm(const u16* __restrict__ A, int lda,
                                              const float* __restrict__ B0, int bstr,
                                              void* __restrict__ C0,
                                              u16* __restrict__ elr,
                                              const float* __restrict__ s0, int M) {
  constexpr int KP = K + 8;
  __shared__ __align__(16) u16 Bt[N * KP];
  int y = blockIdx.y;
  int rrel = (OUTMODE == 3) ? y / NH : y;
  int head = (OUTMODE == 3) ? y % NH : 0;
  const float* B = B0 + (size_t)rrel * bstr;
  const float* scale = s0 + (size_t)rrel * NN;
  const u16* Ab = A + head * HID;
  for (int i = threadIdx.x; i < K * N; i += 256) {
    int k = i / N, n = i % N;
    Bt[n * KP + k] = f2b(B[(size_t)k * N + n]);
  }
  __syncthreads();
  int wid = threadIdx.x >> 6, lane = threadIdx.x & 63;
  int l15 = lane & 15, lg = lane >> 4;
  constexpr int NT = N / 16;
  int ntiles = (M + 63) >> 6;
  for (int tile = blockIdx.x; tile < ntiles; tile += gridDim.x) {
    int mbase = tile * 64 + wid * 16;
    v4f acc[NT];
#pragma unroll
    for (int t = 0; t < NT; ++t) acc[t] = (v4f)(0.f);
    int arow = mbase + l15;
    if (arow >= M) arow = M - 1;
    const u16* ap = Ab + (size_t)arow * lda + lg * 8;
#pragma unroll
    for (int ks = 0; ks < K / 32; ++ks) {
      v8s a = *(const v8s*)(ap + ks * 32);
#pragma unroll
      for (int t = 0; t < NT; ++t) {
        v8s b = *(const v8s*)(&Bt[(t * 16 + l15) * KP + lg * 8 + ks * 32]);
        acc[t] = __builtin_amdgcn_mfma_f32_16x16x32_bf16(a, b, acc[t], 0, 0, 0);
      }
    }
#pragma unroll
    for (int q = 0; q < 4; ++q) {
      int row = mbase + lg * 4 + q;
      if (row >= M) continue;
      if (OUTMODE == 1) {
        float s = scale[row] * QS;
        u8* C = (u8*)C0 + ((size_t)y * M + row) * 64;
#pragma unroll
        for (int t = 0; t < NT; ++t) C[t * 16 + l15] = f2e(acc[t][q] * s);
      } else if (OUTMODE == 2) {
        u32* C = (u32*)C0 + ((size_t)y * M + row) * 64;
#pragma unroll
        for (int tm = 0; tm < 4; ++tm) {
          u32 pk = __builtin_amdgcn_cvt_pk_fp8_f32(acc[tm][q] * QS,
                                                   acc[tm + 4][q] * QS, 0, false);
          pk = __builtin_amdgcn_cvt_pk_fp8_f32(acc[tm + 8][q] * QS, 0.f, pk, true);
          C[tm * 16 + l15] = pk;
        }
        if (l15 < 6)
          elr[((size_t)y * M + row) * 8 + (l15 < 3 ? l15 : l15 + 1)] =
              f2b(acc[12][q]);
      } else {  // OUTMODE 3
        float s = scale[row] * QS;
        u8* C = (u8*)C0 + (((size_t)rrel * M + row) * 64) * 4 + head;
#pragma unroll
        for (int t = 0; t < NT; ++t) C[(t * 16 + l15) * 4] = f2e(acc[t][q] * s);
      }
    }
  }
}

// ======== conv1 gather (fp8, unroll 4) + bias + L2 normalize -> h1b ========
__global__ void k_g1(const int* __restrict__ offs, const int* __restrict__ degd,
                     const int* __restrict__ esrc, const u8* __restrict__ c1pk,
                     const float* __restrict__ nd, const float* __restrict__ b1,
                     u16* __restrict__ h1b) {
  int node = blockIdx.x * 4 + (threadIdx.x >> 6);
  int lane = threadIdx.x & 63;
  if (node >= NN) return;
  float v = 0.f;
#pragma unroll
  for (int r = 0; r < RR; ++r) {
    int start = offs[r * NN + node];
    int deg = degd[r * NN + node];
    const u8* base = c1pk + (size_t)r * NN * 64 + lane;
    float t = 0.f;
    int j = 0;
    for (; j + 4 <= deg; j += 4) {
      int s0 = esrc[start + j], s1 = esrc[start + j + 1];
      int s2 = esrc[start + j + 2], s3 = esrc[start + j + 3];
      float a0 = __builtin_amdgcn_cvt_f32_fp8((u32)base[(size_t)s0 * 64], 0);
      float a1 = __builtin_amdgcn_cvt_f32_fp8((u32)base[(size_t)s1 * 64], 0);
      float a2 = __builtin_amdgcn_cvt_f32_fp8((u32)base[(size_t)s2 * 64], 0);
      float a3 = __builtin_amdgcn_cvt_f32_fp8((u32)base[(size_t)s3 * 64], 0);
      t += (a0 + a1) + (a2 + a3);
    }
    for (; j < deg; ++j)
      t += __builtin_amdgcn_cvt_f32_fp8((u32)base[(size_t)esrc[start + j] * 64], 0);
    v += t * nd[r * NN + node];
  }
  v = v * IQS + b1[lane] + b1[HID + lane] + b1[2 * HID + lane];
  float sq = v * v;
  for (int off = 32; off; off >>= 1) sq += __shfl_xor(sq, off);
  float nrm = sqrtf(sq);
  nrm = nrm > 1e-12f ? nrm : 1e-12f;
  h1b[node * HID + lane] = f2b(v / nrm);
}

// ======== per-edge softmax weights (once per edge) ========
__global__ void k_ew(const int* __restrict__ esrc, const int* __restrict__ edst,
                     const u16* __restrict__ elr, u16* __restrict__ ew) {
  int i = blockIdx.x * 256 + threadIdx.x;
  if (i >= RR * EE) return;
  int r = i / EE;
  int s = esrc[i], d = edst[i];
  const u16* es = elr + ((size_t)(r * NN + s)) * 8;      // el of src
  const u16* ed = elr + ((size_t)(r * NN + d)) * 8 + 4;  // er of dst
  u16x4 o;
  o.x = f2b(wexp(b2f(es[0]) + b2f(ed[0])));
  o.y = f2b(wexp(b2f(es[1]) + b2f(ed[1])));
  o.z = f2b(wexp(b2f(es[2]) + b2f(ed[2])));
  o.w = 0;
  *(u16x4*)(ew + (size_t)i * 4) = o;
}

// ======== GAT gather: packed fp8 rows, unroll 4, + bg + relu -> gatb =====
__global__ void k_gatg(const int* __restrict__ offs, const int* __restrict__ degd,
                       const int* __restrict__ esrc, const u32* __restrict__ fpk,
                       const u16* __restrict__ ew, const float* __restrict__ bg,
                       u16* __restrict__ gatb) {
  int node = blockIdx.x * 4 + (threadIdx.x >> 6);
  int lane = threadIdx.x & 63;
  if (node >= NN) return;
  float o0 = 0.f, o1 = 0.f, o2 = 0.f;
#pragma unroll
  for (int r = 0; r < RR; ++r) {
    const u32* f = fpk + (size_t)r * NN * 64 + lane;
    int start = offs[r * NN + node];
    int deg = degd[r * NN + node];
    float z0 = 0.f, z1 = 0.f, z2 = 0.f;
    float a0 = 0.f, a1 = 0.f, a2 = 0.f;
    int j = 0;
    for (; j + 4 <= deg; j += 4) {
      int p = start + j;
      int s0 = esrc[p], s1 = esrc[p + 1], s2 = esrc[p + 2], s3 = esrc[p + 3];
      u16x4 wa = *(const u16x4*)(ew + (size_t)p * 4);
      u16x4 wb = *(const u16x4*)(ew + (size_t)(p + 1) * 4);
      u16x4 wc = *(const u16x4*)(ew + (size_t)(p + 2) * 4);
      u16x4 wd = *(const u16x4*)(ew + (size_t)(p + 3) * 4);
      u32 v0 = f[(size_t)s0 * 64];
      u32 v1 = f[(size_t)s1 * 64];
      u32 v2 = f[(size_t)s2 * 64];
      u32 v3 = f[(size_t)s3 * 64];
      float w;
      w = b2f(wa.x); z0 += w; a0 += w * __builtin_amdgcn_cvt_f32_fp8(v0, 0);
      w = b2f(wa.y); z1 += w; a1 += w * __builtin_amdgcn_cvt_f32_fp8(v0, 1);
      w = b2f(wa.z); z2 += w; a2 += w * __builtin_amdgcn_cvt_f32_fp8(v0, 2);
      w = b2f(wb.x); z0 += w; a0 += w * __builtin_amdgcn_cvt_f32_fp8(v1, 0);
      w = b2f(wb.y); z1 += w; a1 += w * __builtin_amdgcn_cvt_f32_fp8(v1, 1);
      w = b2f(wb.z); z2 += w; a2 += w * __builtin_amdgcn_cvt_f32_fp8(v1, 2);
      w = b2f(wc.x); z0 += w; a0 += w * __builtin_amdgcn_cvt_f32_fp8(v2, 0);
      w = b2f(wc.y); z1 += w; a1 += w * __builtin_amdgcn_cvt_f32_fp8(v2, 1);
      w = b2f(wc.z); z2 += w; a2 += w * __builtin_amdgcn_cvt_f32_fp8(v2, 2);
      w = b2f(wd.x); z0 += w; a0 += w * __builtin_amdgcn_cvt_f32_fp8(v3, 0);
      w = b2f(wd.y); z1 += w; a1 += w * __builtin_amdgcn_cvt_f32_fp8(v3, 1);
      w = b2f(wd.z); z2 += w; a2 += w * __builtin_amdgcn_cvt_f32_fp8(v3, 2);
    }
    for (; j < deg; ++j) {
      int p = start + j;
      u16x4 wa = *(const u16x4*)(ew + (size_t)p * 4);
      u32 v0 = f[(size_t)esrc[p] * 64];
      float w;
      w = b2f(wa.x); z0 += w; a0 += w * __builtin_amdgcn_cvt_f32_fp8(v0, 0);
      w = b2f(wa.y); z1 += w; a1 += w * __builtin_amdgcn_cvt_f32_fp8(v0, 1);
      w = b2f(wa.z); z2 += w; a2 += w * __builtin_amdgcn_cvt_f32_fp8(v0, 2);
    }
    o0 += a0 / (z0 + 1e-9f);
    o1 += a1 / (z1 + 1e-9f);
    o2 += a2 / (z2 + 1e-9f);
  }
  float ov[NH] = {o0, o1, o2};
#pragma unroll
  for (int h = 0; h < NH; ++h) {
    int j = h * HID + lane;
    float v = ov[h] * IQS + bg[j] + bg[NH * HID + j] + bg[2 * NH * HID + j];
    gatb[(size_t)node * (NH * HID) + j] = f2b(fmaxf(v, 0.f));
  }
}

// ======== conv2 gather: packed fp8 rows, unroll 4, + b2 + sigmoid ========
__global__ void k_g2(const int* __restrict__ offs, const int* __restrict__ degd,
                     const int* __restrict__ esrc, const u32* __restrict__ c2pk,
                     const float* __restrict__ nd, const float* __restrict__ b2,
                     u16* __restrict__ agg2b) {
  int node = blockIdx.x * 4 + (threadIdx.x >> 6);
  int lane = threadIdx.x & 63;
  if (node >= NN) return;
  float o0 = 0.f, o1 = 0.f, o2 = 0.f;
#pragma unroll
  for (int r = 0; r < RR; ++r) {
    const u32* hw = c2pk + (size_t)r * NN * 64 + lane;
    int start = offs[r * NN + node];
    int deg = degd[r * NN + node];
    float a0 = 0.f, a1 = 0.f, a2 = 0.f;
    int j = 0;
    for (; j + 4 <= deg; j += 4) {
      int p = start + j;
      u32 v0 = hw[(size_t)esrc[p] * 64];
      u32 v1 = hw[(size_t)esrc[p + 1] * 64];
      u32 v2 = hw[(size_t)esrc[p + 2] * 64];
      u32 v3 = hw[(size_t)esrc[p + 3] * 64];
      a0 += (__builtin_amdgcn_cvt_f32_fp8(v0, 0) + __builtin_amdgcn_cvt_f32_fp8(v1, 0)) +
            (__builtin_amdgcn_cvt_f32_fp8(v2, 0) + __builtin_amdgcn_cvt_f32_fp8(v3, 0));
      a1 += (__builtin_amdgcn_cvt_f32_fp8(v0, 1) + __builtin_amdgcn_cvt_f32_fp8(v1, 1)) +
            (__builtin_amdgcn_cvt_f32_fp8(v2, 1) + __builtin_amdgcn_cvt_f32_fp8(v3, 1));
      a2 += (__builtin_amdgcn_cvt_f32_fp8(v0, 2) + __builtin_amdgcn_cvt_f32_fp8(v1, 2)) +
            (__builtin_amdgcn_cvt_f32_fp8(v2, 2) + __builtin_amdgcn_cvt_f32_fp8(v3, 2));
    }
    for (; j < deg; ++j) {
      u32 v0 = hw[(size_t)esrc[start + j] * 64];
      a0 += __builtin_amdgcn_cvt_f32_fp8(v0, 0);
      a1 += __builtin_amdgcn_cvt_f32_fp8(v0, 1);
      a2 += __builtin_amdgcn_cvt_f32_fp8(v0, 2);
    }
    float ndv = nd[r * NN + node];
    o0 += a0 * ndv; o1 += a1 * ndv; o2 += a2 * ndv;
  }
  float b2s = b2[lane] + b2[FOUT + lane] + b2[2 * FOUT + lane];
  float ov[NH] = {o0, o1, o2};
#pragma unroll
  for (int h = 0; h < NH; ++h) {
    float v = 1.0f / (1.0f + __expf(-(ov[h] * IQS + b2s)));
    agg2b[(size_t)node * (NH * FOUT) + h * FOUT + lane] = f2b(v);
  }
}

__global__ void k_cnt2(const int* __restrict__ gid, float* __restrict__ cnt) {
  __shared__ int loc[NB];
  if (threadIdx.x < NB) loc[threadIdx.x] = 0;
  __syncthreads();
  int i = blockIdx.x * 256 + threadIdx.x;
  if (i < NN) atomicAdd(&loc[gid[i]], 1);
  __syncthreads();
  if (threadIdx.x < NB) atomicAdd(&cnt[threadIdx.x], (float)loc[threadIdx.x]);
}

__global__ void k_pool(const u16* __restrict__ h3, const int* __restrict__ gid,
                       float* __restrict__ pooled) {
  int j = threadIdx.x;  // 0..191
  int start = blockIdx.x * 128;
  if (start >= NN) return;
  int end = start + 128;
  if (end > NN) end = NN;
  int gcur = gid[start];
  float acc = 0.f;
  for (int n = start; n < end; ++n) {
    int g = gid[n];
    if (g != gcur) {
      atomicAdd(&pooled[gcur * (NH * FOUT) + j], acc);
      acc = 0.f;
      gcur = g;
    }
    acc += b2f(h3[(size_t)n * (NH * FOUT) + j]);
  }
  atomicAdd(&pooled[gcur * (NH * FOUT) + j], acc);
}

__global__ void k_final(const float* __restrict__ pooled, const float* __restrict__ cnt,
                        const float* __restrict__ Wc, const float* __restrict__ bc,
                        float* __restrict__ out) {
  int t = threadIdx.x;
  if (t >= NB * NH) return;
  int b = t / NH;
  float inv = 1.0f / fmaxf(cnt[b], 1.0f);
  const float* p = pooled + t * FOUT;
  float sacc = 0.f;
  for (int c = 0; c < NC; ++c) {
    float acc = bc[c];
    for (int o = 0; o < FOUT; ++o) acc += p[o] * inv * Wc[o * NC + c];
    sacc += 1.0f / (1.0f + __expf(-acc));
  }
  out[t] = sacc * (1.0f / NC);
}

extern "C" void kernel_launch(void* const* d_in, const int* in_sizes, int n_in,
                              void* d_out, int out_size, void* d_ws, size_t ws_size,
                              hipStream_t stream) {
  const float* x = (const float*)d_in[0];
  const int* src = (const int*)d_in[1];
  const int* dst = (const int*)d_in[2];
  const int* gid = (const int*)d_in[3];
  const float* W1 = (const float*)d_in[4];
  const float* b1 = (const float*)d_in[5];
  const float* Wg = (const float*)d_in[6];
  const float* al = (const float*)d_in[7];
  const float* ar = (const float*)d_in[8];
  const float* bg = (const float*)d_in[9];
  const float* W2 = (const float*)d_in[10];
  const float* b2 = (const float*)d_in[11];
  const float* Wc = (const float*)d_in[12];
  const float* bc = (const float*)d_in[13];
  float* out = (float*)d_out;

  // ---- workspace layout (~111 MB; 127 MB proven) ----
  int* degs = (int*)d_ws;                         // 150000
  int* degd = degs + RR * NN;                     // 150000
  float* cnt = (float*)(degd + RR * NN);          // 8
  float* pooled = cnt + NB;                       // 1536
  size_t zero_bytes = ((size_t)2 * RR * NN + NB + NB * NH * FOUT) * 4;
  int* offs = (int*)(pooled + NB * NH * FOUT);    // 150008
  int* cursor = offs + RR * NN + 8;               // 150000
  int* bsum = cursor + RR * NN;                   // 1024
  int* esrc = bsum + 1024;                        // 1200000
  int* edst = esrc + (size_t)RR * EE;             // 1200000
  float* ns = (float*)(edst + (size_t)RR * EE);   // 150000
  float* nd = ns + RR * NN;                       // 150000
  float* Bcomp = nd + RR * NN;                    // 39936
  u16* elr = (u16*)(Bcomp + RR * HID * NGAT);     // RR*NN*8 u16
  u16* ew = elr + (size_t)RR * NN * 8;            // RR*EE*4 u16
  u16* xb = ew + (size_t)RR * EE * 4;             // NN*FIN u16 (12.8MB)
  u16* h1b = xb + (size_t)NN * FIN;               // NN*HID u16 (6.4MB)
  u8* c1pk = (u8*)(h1b + (size_t)NN * HID);       // RR*NN*64 u8 (9.6MB)
  u16* gatb = (u16*)(c1pk + (size_t)RR * NN * 64);  // NN*192 u16 (19.2MB)
  u32* fpk = (u32*)(gatb + (size_t)NN * NH * HID);  // RR*NN*64 u32 (38.4MB)
  u32* c2pk = fpk;   // alias: fpk dead after k_gatg
  u16* agg2b = xb;   // alias: xb+h1b (19.2MB) dead before k_g2 writes

  hipMemsetAsync(d_ws, 0, zero_bytes, stream);

  const int nscan = RR * NN;
  const int nblk1 = (nscan + 255) / 256;

  // degrees + norms + CSR build (with edst)
  k_deg<<<(RR * EE + 255) / 256, 256, 0, stream>>>(src, dst, degs, degd);
  k_norm<<<(nscan + 255) / 256, 256, 0, stream>>>(degs, degd, ns, nd);
  k_scan1<<<nblk1, 256, 0, stream>>>(degd, offs, bsum);
  k_scan2<<<1, 1024, 0, stream>>>(bsum, nblk1);
  k_scan3<<<nblk1, 256, 0, stream>>>(offs, bsum, cursor);
  k_fill<<<(RR * EE + 255) / 256, 256, 0, stream>>>(src, dst, cursor, esrc, edst);

  // casts + composite-B build
  k_cast<<<(NN * FIN / 4 + 255) / 256, 256, 0, stream>>>((const float4*)x, (u16x4*)xb,
                                                         NN * FIN / 4);
  k_bcomp<<<(RR * HID * NGAT + 255) / 256, 256, 0, stream>>>(Wg, al, ar, Bcomp);

  // conv1: MFMA GEMM -> fp8 c1pk; gather+bias+L2norm -> h1b
  k_gemm<FIN, HID, 1><<<dim3(782, RR), 256, 0, stream>>>(
      xb, FIN, W1, FIN * HID, c1pk, nullptr, ns, NN);
  k_g1<<<(NN + 3) / 4, 256, 0, stream>>>(offs, degd, esrc, c1pk, nd, b1, h1b);

  // GAT: GEMM (N=208) -> packed fpk + elr; edge weights; merged gather
  k_gemm<HID, NGAT, 2><<<dim3(782, RR), 256, 0, stream>>>(
      h1b, HID, Bcomp, HID * NGAT, fpk, elr, ns, NN);
  k_ew<<<(RR * EE + 255) / 256, 256, 0, stream>>>(esrc, edst, elr, ew);
  k_gatg<<<(NN + 3) / 4, 256, 0, stream>>>(offs, degd, esrc, fpk, ew, bg, gatb);

  // conv2: GEMM per (r,head) -> byte-lane packed c2pk; merged gather
  k_gemm<HID, FOUT, 3><<<dim3(782, RR * NH), 256, 0, stream>>>(
      gatb, NH * HID, W2, HID * FOUT, c2pk, nullptr, ns, NN);
  k_g2<<<(NN + 3) / 4, 256, 0, stream>>>(offs, degd, esrc, c2pk, nd, b2, agg2b);

  // pooling + classifier
  k_cnt2<<<(NN + 255) / 256, 256, 0, stream>>>(gid, cnt);
  k_pool<<<(NN + 127) / 128, 192, 0, stream>>>(agg2b, gid, pooled);
  k_final<<<1, 64, 0, stream>>>(pooled, cnt, Wc, bc, out);
}

// Round 10
// 552.780 us; speedup vs baseline: 3.9422x; 1.2065x over previous
//
#include <hip/hip_runtime.h>
#include <math.h>

#define NN 50000
#define EE 400000
#define RR 3
#define NH 3
#define FIN 128
#define HID 64
#define FOUT 64
#define NC 16
#define NB 8
#define NGAT 208  // 192 f cols + 6 el/er cols + 10 pad

#define NBLK 32
#define CHK (EE / NBLK)    // 12500 edges per chunk
#define NRNG 4
#define RNGSZ (NN / NRNG)  // 12500 nodes per range

typedef __attribute__((ext_vector_type(8))) short v8s;  // 8 bf16 (4 VGPRs)
typedef __attribute__((ext_vector_type(4))) float v4f;  // MFMA acc
typedef unsigned short u16;
typedef unsigned char u8;
typedef unsigned int u32;
typedef __attribute__((ext_vector_type(4))) unsigned short u16x4;

#define QS 32.0f  // fp8 pre-scale
#define IQS (1.0f / 32.0f)

__device__ __forceinline__ u16 f2b(float f) {  // f32 -> bf16 RNE
  unsigned u = __float_as_uint(f);
  return (u16)((u + 0x7fffu + ((u >> 16) & 1u)) >> 16);
}
__device__ __forceinline__ float b2f(u16 b) {
  return __uint_as_float(((unsigned)b) << 16);
}
__device__ __forceinline__ float wexp(float e) {  // leaky_relu(0.2) then exp
  e = e > 0.f ? e : 0.2f * e;
  return __expf(e);
}
__device__ __forceinline__ u8 f2e(float v) {  // f32 -> fp8 (HW)
  return (u8)(__builtin_amdgcn_cvt_pk_fp8_f32(v, 0.f, 0, false) & 0xff);
}

// ======== LDS-privatized histogram; zero global atomics ========
// grid (NBLK, 8, RR): y>>2 = kind (0=src counts, 1=dst counts+rank), y&3 = range
__global__ __launch_bounds__(1024) void k_hist(const int* __restrict__ src,
                                               const int* __restrict__ dst,
                                               u16* __restrict__ ps,
                                               u16* __restrict__ pd,
                                               u16* __restrict__ rank) {
  __shared__ u32 h[RNGSZ];  // 50 KB
  int b = blockIdx.x;
  int kind = blockIdx.y >> 2, range = blockIdx.y & 3;
  int r = blockIdx.z;
  int lo = range * RNGSZ;
  for (int i = threadIdx.x; i < RNGSZ; i += 1024) h[i] = 0;
  __syncthreads();
  int base = r * EE + b * CHK;
  if (kind) {
    for (int i = threadIdx.x; i < CHK; i += 1024) {
      int d = dst[base + i] - lo;
      if ((unsigned)d < RNGSZ) rank[base + i] = (u16)atomicAdd(&h[d], 1u);
    }
  } else {
    for (int i = threadIdx.x; i < CHK; i += 1024) {
      int s = src[base + i] - lo;
      if ((unsigned)s < RNGSZ) atomicAdd(&h[s], 1u);
    }
  }
  __syncthreads();
  u16* p = (kind ? pd : ps) + (size_t)(r * NBLK + b) * NN + lo;
  for (int i = threadIdx.x; i < RNGSZ; i += 1024) p[i] = (u16)h[i];
}

// ======== reduce partials -> degd, ns, nd, per-block prefixes ========
__global__ void k_red(const u16* __restrict__ ps, const u16* __restrict__ pd,
                      int* __restrict__ degd, float* __restrict__ ns,
                      float* __restrict__ nd, u16* __restrict__ bpfx) {
  int i = blockIdx.x * 256 + threadIdx.x;  // r*NN+n
  if (i >= RR * NN) return;
  int r = i / NN, n = i - r * NN;
  u32 ss = 0, sd = 0;
  for (int b = 0; b < NBLK; ++b) {
    size_t o = (size_t)(r * NBLK + b) * NN + n;
    ss += ps[o];
    bpfx[o] = (u16)sd;
    sd += pd[o];
  }
  degd[i] = (int)sd;
  ns[i] = 1.0f / sqrtf((float)(ss > 1 ? ss : 1));
  nd[i] = 1.0f / sqrtf((float)(sd > 1 ? sd : 1));
}

// ======== exclusive scan (3 kernels) ========
__global__ void k_scan1(const int* __restrict__ deg, int* __restrict__ offs,
                        int* __restrict__ bsum) {
  __shared__ int sh[256];
  int gid = blockIdx.x * 256 + threadIdx.x;
  int v = (gid < RR * NN) ? deg[gid] : 0;
  sh[threadIdx.x] = v;
  __syncthreads();
  for (int off = 1; off < 256; off <<= 1) {
    int t = (threadIdx.x >= off) ? sh[threadIdx.x - off] : 0;
    __syncthreads();
    sh[threadIdx.x] += t;
    __syncthreads();
  }
  if (gid < RR * NN) offs[gid] = sh[threadIdx.x] - v;
  if (threadIdx.x == 255) bsum[blockIdx.x] = sh[255];
}

__global__ void k_scan2(int* __restrict__ bsum, int nb) {
  __shared__ int sh[1024];
  int v = (threadIdx.x < nb) ? bsum[threadIdx.x] : 0;
  sh[threadIdx.x] = v;
  __syncthreads();
  for (int off = 1; off < 1024; off <<= 1) {
    int t = (threadIdx.x >= off) ? sh[threadIdx.x - off] : 0;
    __syncthreads();
    sh[threadIdx.x] += t;
    __syncthreads();
  }
  if (threadIdx.x < nb) bsum[threadIdx.x] = sh[threadIdx.x] - v;
}

__global__ void k_scan3(int* __restrict__ offs, const int* __restrict__ bsum) {
  int i = blockIdx.x * 256 + threadIdx.x;
  if (i >= RR * NN) return;
  offs[i] = offs[i] + bsum[i / 256];
}

// ======== place edges (no atomics): pos = offs + bpfx + rank ========
__global__ __launch_bounds__(1024) void k_place(const int* __restrict__ src,
                                                const int* __restrict__ dst,
                                                const int* __restrict__ offs,
                                                const u16* __restrict__ bpfx,
                                                const u16* __restrict__ rank,
                                                int* __restrict__ esrc) {
  int b = blockIdx.x;
  int range = blockIdx.y;
  int r = blockIdx.z;
  int lo = range * RNGSZ;
  int base = r * EE + b * CHK;
  for (int i = threadIdx.x; i < CHK; i += 1024) {
    int d = dst[base + i] - lo;
    if ((unsigned)d < RNGSZ) {
      int dg = d + lo;
      size_t o = (size_t)(r * NBLK + b) * NN + dg;
      int pos = offs[r * NN + dg] + (int)bpfx[o] + (int)rank[base + i];
      esrc[pos] = src[base + i];
    }
  }
}

// ======== f32 -> bf16 cast ========
__global__ void k_cast(const float4* __restrict__ in, u16x4* __restrict__ out, int n4) {
  int i = blockIdx.x * 256 + threadIdx.x;
  if (i >= n4) return;
  float4 v = in[i];
  u16x4 o;
  o.x = f2b(v.x); o.y = f2b(v.y); o.z = f2b(v.z); o.w = f2b(v.w);
  out[i] = o;
}

// ======== Bcomp: [r][k][208] = [Wg | Wg.al (3) | Wg.ar (3) | 0 pad] ========
__global__ void k_bcomp(const float* __restrict__ Wg, const float* __restrict__ al,
                        const float* __restrict__ ar, float* __restrict__ B) {
  int i = blockIdx.x * 256 + threadIdx.x;
  if (i >= RR * HID * NGAT) return;
  int col = i % NGAT;
  int k = (i / NGAT) % HID;
  int r = i / (NGAT * HID);
  float v = 0.f;
  if (col < NH * HID) {
    v = Wg[((size_t)(r * HID + k)) * (NH * HID) + col];
  } else if (col < NH * HID + 6) {
    int c2 = col - NH * HID;
    int isar = c2 / NH, h = c2 % NH;
    const float* wg = Wg + ((size_t)(r * HID + k)) * (NH * HID) + h * HID;
    const float* av = (isar ? ar : al) + (r * NH + h) * HID;
    float a = 0.f;
#pragma unroll 8
    for (int c = 0; c < HID; ++c) a += wg[c] * av[c];
    v = a;
  }
  B[i] = v;
}

// ======== MFMA GEMM with fp8-pack epilogues ========
// OUTMODE 1: conv1 -> u8 C[(y*M+row)*64+col] = fp8(acc*scale[row]*QS)
// OUTMODE 2: GAT   -> u32 C[(y*M+row)*64+c64] bytes=heads (fp8*QS); tile12 -> elr bf16
// OUTMODE 3: conv2 -> u8 at ((r*M+row)*64+col)*4+head, fp8(acc*scale[row]*QS)
template <int K, int N, int OUTMODE>
__global__ __launch_bounds__(256) void k_gemm(const u16* __restrict__ A, int lda,
                                              const float* __restrict__ B0, int bstr,
                                              void* __restrict__ C0,
                                              u16* __restrict__ elr,
                                              const float* __restrict__ s0, int M) {
  constexpr int KP = K + 8;
  __shared__ __align__(16) u16 Bt[N * KP];
  int y = blockIdx.y;
  int rrel = (OUTMODE == 3) ? y / NH : y;
  int head = (OUTMODE == 3) ? y % NH : 0;
  const float* B = B0 + (size_t)rrel * bstr;
  const float* scale = s0 + (size_t)rrel * NN;
  const u16* Ab = A + head * HID;
  for (int i = threadIdx.x; i < K * N; i += 256) {
    int k = i / N, n = i % N;
    Bt[n * KP + k] = f2b(B[(size_t)k * N + n]);
  }
  __syncthreads();
  int wid = threadIdx.x >> 6, lane = threadIdx.x & 63;
  int l15 = lane & 15, lg = lane >> 4;
  constexpr int NT = N / 16;
  int ntiles = (M + 63) >> 6;
  for (int tile = blockIdx.x; tile < ntiles; tile += gridDim.x) {
    int mbase = tile * 64 + wid * 16;
    v4f acc[NT];
#pragma unroll
    for (int t = 0; t < NT; ++t) acc[t] = (v4f)(0.f);
    int arow = mbase + l15;
    if (arow >= M) arow = M - 1;
    const u16* ap = Ab + (size_t)arow * lda + lg * 8;
#pragma unroll
    for (int ks = 0; ks < K / 32; ++ks) {
      v8s a = *(const v8s*)(ap + ks * 32);
#pragma unroll
      for (int t = 0; t < NT; ++t) {
        v8s b = *(const v8s*)(&Bt[(t * 16 + l15) * KP + lg * 8 + ks * 32]);
        acc[t] = __builtin_amdgcn_mfma_f32_16x16x32_bf16(a, b, acc[t], 0, 0, 0);
      }
    }
#pragma unroll
    for (int q = 0; q < 4; ++q) {
      int row = mbase + lg * 4 + q;
      if (row >= M) continue;
      if (OUTMODE == 1) {
        float s = scale[row] * QS;
        u8* C = (u8*)C0 + ((size_t)y * M + row) * 64;
#pragma unroll
        for (int t = 0; t < NT; ++t) C[t * 16 + l15] = f2e(acc[t][q] * s);
      } else if (OUTMODE == 2) {
        u32* C = (u32*)C0 + ((size_t)y * M + row) * 64;
#pragma unroll
        for (int tm = 0; tm < 4; ++tm) {
          u32 pk = __builtin_amdgcn_cvt_pk_fp8_f32(acc[tm][q] * QS,
                                                   acc[tm + 4][q] * QS, 0, false);
          pk = __builtin_amdgcn_cvt_pk_fp8_f32(acc[tm + 8][q] * QS, 0.f, pk, true);
          C[tm * 16 + l15] = pk;
        }
        if (l15 < 6)
          elr[((size_t)y * M + row) * 8 + (l15 < 3 ? l15 : l15 + 1)] =
              f2b(acc[12][q]);
      } else {  // OUTMODE 3
        float s = scale[row] * QS;
        u8* C = (u8*)C0 + (((size_t)rrel * M + row) * 64) * 4 + head;
#pragma unroll
        for (int t = 0; t < NT; ++t) C[(t * 16 + l15) * 4] = f2e(acc[t][q] * s);
      }
    }
  }
}

// ======== conv1 gather (fp8, unroll 4) + bias + L2 normalize -> h1b ========
__global__ void k_g1(const int* __restrict__ offs, const int* __restrict__ degd,
                     const int* __restrict__ esrc, const u8* __restrict__ c1pk,
                     const float* __restrict__ nd, const float* __restrict__ b1,
                     u16* __restrict__ h1b) {
  int node = blockIdx.x * 4 + (threadIdx.x >> 6);
  int lane = threadIdx.x & 63;
  if (node >= NN) return;
  float v = 0.f;
#pragma unroll
  for (int r = 0; r < RR; ++r) {
    int start = offs[r * NN + node];
    int deg = degd[r * NN + node];
    const u8* base = c1pk + (size_t)r * NN * 64 + lane;
    float t = 0.f;
    int j = 0;
    for (; j + 4 <= deg; j += 4) {
      int s0 = esrc[start + j], s1 = esrc[start + j + 1];
      int s2 = esrc[start + j + 2], s3 = esrc[start + j + 3];
      float a0 = __builtin_amdgcn_cvt_f32_fp8((u32)base[(size_t)s0 * 64], 0);
      float a1 = __builtin_amdgcn_cvt_f32_fp8((u32)base[(size_t)s1 * 64], 0);
      float a2 = __builtin_amdgcn_cvt_f32_fp8((u32)base[(size_t)s2 * 64], 0);
      float a3 = __builtin_amdgcn_cvt_f32_fp8((u32)base[(size_t)s3 * 64], 0);
      t += (a0 + a1) + (a2 + a3);
    }
    for (; j < deg; ++j)
      t += __builtin_amdgcn_cvt_f32_fp8((u32)base[(size_t)esrc[start + j] * 64], 0);
    v += t * nd[r * NN + node];
  }
  v = v * IQS + b1[lane] + b1[HID + lane] + b1[2 * HID + lane];
  float sq = v * v;
  for (int off = 32; off; off >>= 1) sq += __shfl_xor(sq, off);
  float nrm = sqrtf(sq);
  nrm = nrm > 1e-12f ? nrm : 1e-12f;
  h1b[node * HID + lane] = f2b(v / nrm);
}

// ======== per-edge softmax weights, node-parallel over CSR (no edst) ========
__global__ void k_ew(const int* __restrict__ offs, const int* __restrict__ degd,
                     const int* __restrict__ esrc, const u16* __restrict__ elr,
                     u16* __restrict__ ew) {
  int i = blockIdx.x * 256 + threadIdx.x;  // r*NN + node
  if (i >= RR * NN) return;
  int r = i / NN;
  int start = offs[i], deg = degd[i];
  const u16* ed = elr + (size_t)i * 8 + 4;  // er of dst
  float e0 = b2f(ed[0]), e1 = b2f(ed[1]), e2 = b2f(ed[2]);
  for (int j = 0; j < deg; ++j) {
    int s = esrc[start + j];
    const u16* es = elr + ((size_t)r * NN + s) * 8;  // el of src
    u16x4 o;
    o.x = f2b(wexp(b2f(es[0]) + e0));
    o.y = f2b(wexp(b2f(es[1]) + e1));
    o.z = f2b(wexp(b2f(es[2]) + e2));
    o.w = 0;
    *(u16x4*)(ew + (size_t)(start + j) * 4) = o;
  }
}

// ======== GAT gather: packed fp8 rows, unroll 4, + bg + relu -> gatb =====
__global__ void k_gatg(const int* __restrict__ offs, const int* __restrict__ degd,
                       const int* __restrict__ esrc, const u32* __restrict__ fpk,
                       const u16* __restrict__ ew, const float* __restrict__ bg,
                       u16* __restrict__ gatb) {
  int node = blockIdx.x * 4 + (threadIdx.x >> 6);
  int lane = threadIdx.x & 63;
  if (node >= NN) return;
  float o0 = 0.f, o1 = 0.f, o2 = 0.f;
#pragma unroll
  for (int r = 0; r < RR; ++r) {
    const u32* f = fpk + (size_t)r * NN * 64 + lane;
    int start = offs[r * NN + node];
    int deg = degd[r * NN + node];
    float z0 = 0.f, z1 = 0.f, z2 = 0.f;
    float a0 = 0.f, a1 = 0.f, a2 = 0.f;
    int j = 0;
    for (; j + 4 <= deg; j += 4) {
      int p = start + j;
      int s0 = esrc[p], s1 = esrc[p + 1], s2 = esrc[p + 2], s3 = esrc[p + 3];
      u16x4 wa = *(const u16x4*)(ew + (size_t)p * 4);
      u16x4 wb = *(const u16x4*)(ew + (size_t)(p + 1) * 4);
      u16x4 wc = *(const u16x4*)(ew + (size_t)(p + 2) * 4);
      u16x4 wd = *(const u16x4*)(ew + (size_t)(p + 3) * 4);
      u32 v0 = f[(size_t)s0 * 64];
      u32 v1 = f[(size_t)s1 * 64];
      u32 v2 = f[(size_t)s2 * 64];
      u32 v3 = f[(size_t)s3 * 64];
      float w;
      w = b2f(wa.x); z0 += w; a0 += w * __builtin_amdgcn_cvt_f32_fp8(v0, 0);
      w = b2f(wa.y); z1 += w; a1 += w * __builtin_amdgcn_cvt_f32_fp8(v0, 1);
      w = b2f(wa.z); z2 += w; a2 += w * __builtin_amdgcn_cvt_f32_fp8(v0, 2);
      w = b2f(wb.x); z0 += w; a0 += w * __builtin_amdgcn_cvt_f32_fp8(v1, 0);
      w = b2f(wb.y); z1 += w; a1 += w * __builtin_amdgcn_cvt_f32_fp8(v1, 1);
      w = b2f(wb.z); z2 += w; a2 += w * __builtin_amdgcn_cvt_f32_fp8(v1, 2);
      w = b2f(wc.x); z0 += w; a0 += w * __builtin_amdgcn_cvt_f32_fp8(v2, 0);
      w = b2f(wc.y); z1 += w; a1 += w * __builtin_amdgcn_cvt_f32_fp8(v2, 1);
      w = b2f(wc.z); z2 += w; a2 += w * __builtin_amdgcn_cvt_f32_fp8(v2, 2);
      w = b2f(wd.x); z0 += w; a0 += w * __builtin_amdgcn_cvt_f32_fp8(v3, 0);
      w = b2f(wd.y); z1 += w; a1 += w * __builtin_amdgcn_cvt_f32_fp8(v3, 1);
      w = b2f(wd.z); z2 += w; a2 += w * __builtin_amdgcn_cvt_f32_fp8(v3, 2);
    }
    for (; j < deg; ++j) {
      int p = start + j;
      u16x4 wa = *(const u16x4*)(ew + (size_t)p * 4);
      u32 v0 = f[(size_t)esrc[p] * 64];
      float w;
      w = b2f(wa.x); z0 += w; a0 += w * __builtin_amdgcn_cvt_f32_fp8(v0, 0);
      w = b2f(wa.y); z1 += w; a1 += w * __builtin_amdgcn_cvt_f32_fp8(v0, 1);
      w = b2f(wa.z); z2 += w; a2 += w * __builtin_amdgcn_cvt_f32_fp8(v0, 2);
    }
    o0 += a0 / (z0 + 1e-9f);
    o1 += a1 / (z1 + 1e-9f);
    o2 += a2 / (z2 + 1e-9f);
  }
  float ov[NH] = {o0, o1, o2};
#pragma unroll
  for (int h = 0; h < NH; ++h) {
    int j = h * HID + lane;
    float v = ov[h] * IQS + bg[j] + bg[NH * HID + j] + bg[2 * NH * HID + j];
    gatb[(size_t)node * (NH * HID) + j] = f2b(fmaxf(v, 0.f));
  }
}

// ======== conv2 gather: packed fp8 rows, unroll 4, + b2 + sigmoid ========
__global__ void k_g2(const int* __restrict__ offs, const int* __restrict__ degd,
                     const int* __restrict__ esrc, const u32* __restrict__ c2pk,
                     const float* __restrict__ nd, const float* __restrict__ b2,
                     u16* __restrict__ agg2b) {
  int node = blockIdx.x * 4 + (threadIdx.x >> 6);
  int lane = threadIdx.x & 63;
  if (node >= NN) return;
  float o0 = 0.f, o1 = 0.f, o2 = 0.f;
#pragma unroll
  for (int r = 0; r < RR; ++r) {
    const u32* hw = c2pk + (size_t)r * NN * 64 + lane;
    int start = offs[r * NN + node];
    int deg = degd[r * NN + node];
    float a0 = 0.f, a1 = 0.f, a2 = 0.f;
    int j = 0;
    for (; j + 4 <= deg; j += 4) {
      int p = start + j;
      u32 v0 = hw[(size_t)esrc[p] * 64];
      u32 v1 = hw[(size_t)esrc[p + 1] * 64];
      u32 v2 = hw[(size_t)esrc[p + 2] * 64];
      u32 v3 = hw[(size_t)esrc[p + 3] * 64];
      a0 += (__builtin_amdgcn_cvt_f32_fp8(v0, 0) + __builtin_amdgcn_cvt_f32_fp8(v1, 0)) +
            (__builtin_amdgcn_cvt_f32_fp8(v2, 0) + __builtin_amdgcn_cvt_f32_fp8(v3, 0));
      a1 += (__builtin_amdgcn_cvt_f32_fp8(v0, 1) + __builtin_amdgcn_cvt_f32_fp8(v1, 1)) +
            (__builtin_amdgcn_cvt_f32_fp8(v2, 1) + __builtin_amdgcn_cvt_f32_fp8(v3, 1));
      a2 += (__builtin_amdgcn_cvt_f32_fp8(v0, 2) + __builtin_amdgcn_cvt_f32_fp8(v1, 2)) +
            (__builtin_amdgcn_cvt_f32_fp8(v2, 2) + __builtin_amdgcn_cvt_f32_fp8(v3, 2));
    }
    for (; j < deg; ++j) {
      u32 v0 = hw[(size_t)esrc[start + j] * 64];
      a0 += __builtin_amdgcn_cvt_f32_fp8(v0, 0);
      a1 += __builtin_amdgcn_cvt_f32_fp8(v0, 1);
      a2 += __builtin_amdgcn_cvt_f32_fp8(v0, 2);
    }
    float ndv = nd[r * NN + node];
    o0 += a0 * ndv; o1 += a1 * ndv; o2 += a2 * ndv;
  }
  float b2s = b2[lane] + b2[FOUT + lane] + b2[2 * FOUT + lane];
  float ov[NH] = {o0, o1, o2};
#pragma unroll
  for (int h = 0; h < NH; ++h) {
    float v = 1.0f / (1.0f + __expf(-(ov[h] * IQS + b2s)));
    agg2b[(size_t)node * (NH * FOUT) + h * FOUT + lane] = f2b(v);
  }
}

__global__ void k_cnt2(const int* __restrict__ gid, float* __restrict__ cnt) {
  __shared__ int loc[NB];
  if (threadIdx.x < NB) loc[threadIdx.x] = 0;
  __syncthreads();
  int i = blockIdx.x * 256 + threadIdx.x;
  if (i < NN) atomicAdd(&loc[gid[i]], 1);
  __syncthreads();
  if (threadIdx.x < NB) atomicAdd(&cnt[threadIdx.x], (float)loc[threadIdx.x]);
}

__global__ void k_pool(const u16* __restrict__ h3, const int* __restrict__ gid,
                       float* __restrict__ pooled) {
  int j = threadIdx.x;  // 0..191
  int start = blockIdx.x * 128;
  if (start >= NN) return;
  int end = start + 128;
  if (end > NN) end = NN;
  int gcur = gid[start];
  float acc = 0.f;
  for (int n = start; n < end; ++n) {
    int g = gid[n];
    if (g != gcur) {
      atomicAdd(&pooled[gcur * (NH * FOUT) + j], acc);
      acc = 0.f;
      gcur = g;
    }
    acc += b2f(h3[(size_t)n * (NH * FOUT) + j]);
  }
  atomicAdd(&pooled[gcur * (NH * FOUT) + j], acc);
}

__global__ void k_final(const float* __restrict__ pooled, const float* __restrict__ cnt,
                        const float* __restrict__ Wc, const float* __restrict__ bc,
                        float* __restrict__ out) {
  int t = threadIdx.x;
  if (t >= NB * NH) return;
  int b = t / NH;
  float inv = 1.0f / fmaxf(cnt[b], 1.0f);
  const float* p = pooled + t * FOUT;
  float sacc = 0.f;
  for (int c = 0; c < NC; ++c) {
    float acc = bc[c];
    for (int o = 0; o < FOUT; ++o) acc += p[o] * inv * Wc[o * NC + c];
    sacc += 1.0f / (1.0f + __expf(-acc));
  }
  out[t] = sacc * (1.0f / NC);
}

extern "C" void kernel_launch(void* const* d_in, const int* in_sizes, int n_in,
                              void* d_out, int out_size, void* d_ws, size_t ws_size,
                              hipStream_t stream) {
  const float* x = (const float*)d_in[0];
  const int* src = (const int*)d_in[1];
  const int* dst = (const int*)d_in[2];
  const int* gid = (const int*)d_in[3];
  const float* W1 = (const float*)d_in[4];
  const float* b1 = (const float*)d_in[5];
  const float* Wg = (const float*)d_in[6];
  const float* al = (const float*)d_in[7];
  const float* ar = (const float*)d_in[8];
  const float* bg = (const float*)d_in[9];
  const float* W2 = (const float*)d_in[10];
  const float* b2 = (const float*)d_in[11];
  const float* Wc = (const float*)d_in[12];
  const float* bc = (const float*)d_in[13];
  float* out = (float*)d_out;

  // ---- workspace layout (~106 MB; 127 MB proven) ----
  float* cnt = (float*)d_ws;                      // 8
  float* pooled = cnt + NB;                       // 1536
  size_t zero_bytes = ((size_t)NB + NB * NH * FOUT) * 4;
  int* degd = (int*)(pooled + NB * NH * FOUT);    // 150000
  int* offs = degd + RR * NN;                     // 150000 (+8 pad)
  int* bsum = offs + RR * NN + 8;                 // 1024
  int* esrc = bsum + 1024;                        // 1200000
  float* ns = (float*)(esrc + (size_t)RR * EE);   // 150000
  float* nd = ns + RR * NN;                       // 150000
  float* Bcomp = nd + RR * NN;                    // 39936
  u16* elr = (u16*)(Bcomp + RR * HID * NGAT);     // RR*NN*8 u16 (2.4MB)
  u16* ew = elr + (size_t)RR * NN * 8;            // RR*EE*4 u16 (9.6MB)
  u16* xb = ew + (size_t)RR * EE * 4;             // NN*FIN u16 (12.8MB)
  u16* h1b = xb + (size_t)NN * FIN;               // NN*HID u16 (6.4MB)
  u8* c1pk = (u8*)(h1b + (size_t)NN * HID);       // RR*NN*64 u8 (9.6MB)
  u16* gatb = (u16*)(c1pk + (size_t)RR * NN * 64);  // NN*192 u16 (19.2MB)
  u32* fpk = (u32*)(gatb + (size_t)NN * NH * HID);  // RR*NN*64 u32 (38.4MB)
  u32* c2pk = fpk;  // alias: fpk dead after k_gatg
  u16* agg2b = xb;  // alias: xb+h1b (19.2MB) dead before k_g2 writes
  // CSR-build scratch aliases fpk (dead until gemm2): 31.2MB <= 38.4MB
  u16* ps = (u16*)fpk;                            // RR*NBLK*NN u16 (9.6MB)
  u16* pd = ps + (size_t)RR * NBLK * NN;          // 9.6MB
  u16* bpfx = pd + (size_t)RR * NBLK * NN;        // 9.6MB
  u16* rank = bpfx + (size_t)RR * NBLK * NN;      // RR*EE u16 (2.4MB)

  hipMemsetAsync(d_ws, 0, zero_bytes, stream);

  const int nscan = RR * NN;
  const int nblk1 = (nscan + 255) / 256;

  // CSR build: LDS histograms -> reduce -> scan -> place (no global atomics)
  k_hist<<<dim3(NBLK, 8, RR), 1024, 0, stream>>>(src, dst, ps, pd, rank);
  k_red<<<nblk1, 256, 0, stream>>>(ps, pd, degd, ns, nd, bpfx);
  k_scan1<<<nblk1, 256, 0, stream>>>(degd, offs, bsum);
  k_scan2<<<1, 1024, 0, stream>>>(bsum, nblk1);
  k_scan3<<<nblk1, 256, 0, stream>>>(offs, bsum);
  k_place<<<dim3(NBLK, NRNG, RR), 1024, 0, stream>>>(src, dst, offs, bpfx, rank, esrc);

  // casts + composite-B build
  k_cast<<<(NN * FIN / 4 + 255) / 256, 256, 0, stream>>>((const float4*)x, (u16x4*)xb,
                                                         NN * FIN / 4);
  k_bcomp<<<(RR * HID * NGAT + 255) / 256, 256, 0, stream>>>(Wg, al, ar, Bcomp);

  // conv1: MFMA GEMM -> fp8 c1pk; gather+bias+L2norm -> h1b
  k_gemm<FIN, HID, 1><<<dim3(782, RR), 256, 0, stream>>>(
      xb, FIN, W1, FIN * HID, c1pk, nullptr, ns, NN);
  k_g1<<<(NN + 3) / 4, 256, 0, stream>>>(offs, degd, esrc, c1pk, nd, b1, h1b);

  // GAT: GEMM (N=208) -> packed fpk + elr; CSR edge weights; merged gather
  k_gemm<HID, NGAT, 2><<<dim3(782, RR), 256, 0, stream>>>(
      h1b, HID, Bcomp, HID * NGAT, fpk, elr, ns, NN);
  k_ew<<<nblk1, 256, 0, stream>>>(offs, degd, esrc, elr, ew);
  k_gatg<<<(NN + 3) / 4, 256, 0, stream>>>(offs, degd, esrc, fpk, ew, bg, gatb);

  // conv2: GEMM per (r,head) -> byte-lane packed c2pk; merged gather
  k_gemm<HID, FOUT, 3><<<dim3(782, RR * NH), 256, 0, stream>>>(
      gatb, NH * HID, W2, HID * FOUT, c2pk, nullptr, ns, NN);
  k_g2<<<(NN + 3) / 4, 256, 0, stream>>>(offs, degd, esrc, c2pk, nd, b2, agg2b);

  // pooling + classifier
  k_cnt2<<<(NN + 255) / 256, 256, 0, stream>>>(gid, cnt);
  k_pool<<<(NN + 127) / 128, 192, 0, stream>>>(agg2b, gid, pooled);
  k_final<<<1, 64, 0, stream>>>(pooled, cnt, Wc, bc, out);
}

// Round 11
// 549.766 us; speedup vs baseline: 3.9638x; 1.0055x over previous
//
#include <hip/hip_runtime.h>
#include <math.h>

#define NN 50000
#define EE 400000
#define RR 3
#define NH 3
#define FIN 128
#define HID 64
#define FOUT 64
#define NC 16
#define NB 8

#define NBLK 32
#define CHK (EE / NBLK)    // 12500 edges per chunk
#define NRNG 4
#define RNGSZ (NN / NRNG)  // 12500 nodes per range

typedef __attribute__((ext_vector_type(8))) short v8s;  // 8 bf16 (4 VGPRs)
typedef __attribute__((ext_vector_type(4))) float v4f;  // MFMA acc
typedef unsigned short u16;
typedef unsigned char u8;
typedef unsigned int u32;
typedef __attribute__((ext_vector_type(4))) unsigned short u16x4;

#define QS 32.0f  // fp8 pre-scale
#define IQS (1.0f / 32.0f)

__device__ __forceinline__ u16 f2b(float f) {  // f32 -> bf16 RNE
  unsigned u = __float_as_uint(f);
  return (u16)((u + 0x7fffu + ((u >> 16) & 1u)) >> 16);
}
__device__ __forceinline__ float b2f(u16 b) {
  return __uint_as_float(((unsigned)b) << 16);
}
__device__ __forceinline__ float wexp(float e) {  // leaky_relu(0.2) then exp
  e = e > 0.f ? e : 0.2f * e;
  return __expf(e);
}
__device__ __forceinline__ u8 f2e(float v) {  // f32 -> fp8 (HW)
  return (u8)(__builtin_amdgcn_cvt_pk_fp8_f32(v, 0.f, 0, false) & 0xff);
}

// ======== LDS-privatized histogram; zero global atomics ========
__global__ __launch_bounds__(1024) void k_hist(const int* __restrict__ src,
                                               const int* __restrict__ dst,
                                               u16* __restrict__ ps,
                                               u16* __restrict__ pd,
                                               u16* __restrict__ rank) {
  __shared__ u32 h[RNGSZ];  // 50 KB
  int b = blockIdx.x;
  int kind = blockIdx.y >> 2, range = blockIdx.y & 3;
  int r = blockIdx.z;
  int lo = range * RNGSZ;
  for (int i = threadIdx.x; i < RNGSZ; i += 1024) h[i] = 0;
  __syncthreads();
  int base = r * EE + b * CHK;
  if (kind) {
    for (int i = threadIdx.x; i < CHK; i += 1024) {
      int d = dst[base + i] - lo;
      if ((unsigned)d < RNGSZ) rank[base + i] = (u16)atomicAdd(&h[d], 1u);
    }
  } else {
    for (int i = threadIdx.x; i < CHK; i += 1024) {
      int s = src[base + i] - lo;
      if ((unsigned)s < RNGSZ) atomicAdd(&h[s], 1u);
    }
  }
  __syncthreads();
  u16* p = (kind ? pd : ps) + (size_t)(r * NBLK + b) * NN + lo;
  for (int i = threadIdx.x; i < RNGSZ; i += 1024) p[i] = (u16)h[i];
}

__global__ void k_red(const u16* __restrict__ ps, const u16* __restrict__ pd,
                      int* __restrict__ degd, float* __restrict__ ns,
                      float* __restrict__ nd, u16* __restrict__ bpfx) {
  int i = blockIdx.x * 256 + threadIdx.x;  // r*NN+n
  if (i >= RR * NN) return;
  int r = i / NN, n = i - r * NN;
  u32 ss = 0, sd = 0;
  for (int b = 0; b < NBLK; ++b) {
    size_t o = (size_t)(r * NBLK + b) * NN + n;
    ss += ps[o];
    bpfx[o] = (u16)sd;
    sd += pd[o];
  }
  degd[i] = (int)sd;
  ns[i] = 1.0f / sqrtf((float)(ss > 1 ? ss : 1));
  nd[i] = 1.0f / sqrtf((float)(sd > 1 ? sd : 1));
}

__global__ void k_scan1(const int* __restrict__ deg, int* __restrict__ offs,
                        int* __restrict__ bsum) {
  __shared__ int sh[256];
  int gid = blockIdx.x * 256 + threadIdx.x;
  int v = (gid < RR * NN) ? deg[gid] : 0;
  sh[threadIdx.x] = v;
  __syncthreads();
  for (int off = 1; off < 256; off <<= 1) {
    int t = (threadIdx.x >= off) ? sh[threadIdx.x - off] : 0;
    __syncthreads();
    sh[threadIdx.x] += t;
    __syncthreads();
  }
  if (gid < RR * NN) offs[gid] = sh[threadIdx.x] - v;
  if (threadIdx.x == 255) bsum[blockIdx.x] = sh[255];
}

__global__ void k_scan2(int* __restrict__ bsum, int nb) {
  __shared__ int sh[1024];
  int v = (threadIdx.x < nb) ? bsum[threadIdx.x] : 0;
  sh[threadIdx.x] = v;
  __syncthreads();
  for (int off = 1; off < 1024; off <<= 1) {
    int t = (threadIdx.x >= off) ? sh[threadIdx.x - off] : 0;
    __syncthreads();
    sh[threadIdx.x] += t;
    __syncthreads();
  }
  if (threadIdx.x < nb) bsum[threadIdx.x] = sh[threadIdx.x] - v;
}

__global__ void k_scan3(int* __restrict__ offs, const int* __restrict__ bsum) {
  int i = blockIdx.x * 256 + threadIdx.x;
  if (i >= RR * NN) return;
  offs[i] = offs[i] + bsum[i / 256];
}

__global__ __launch_bounds__(1024) void k_place(const int* __restrict__ src,
                                                const int* __restrict__ dst,
                                                const int* __restrict__ offs,
                                                const u16* __restrict__ bpfx,
                                                const u16* __restrict__ rank,
                                                int* __restrict__ esrc) {
  int b = blockIdx.x;
  int range = blockIdx.y;
  int r = blockIdx.z;
  int lo = range * RNGSZ;
  int base = r * EE + b * CHK;
  for (int i = threadIdx.x; i < CHK; i += 1024) {
    int d = dst[base + i] - lo;
    if ((unsigned)d < RNGSZ) {
      int dg = d + lo;
      size_t o = (size_t)(r * NBLK + b) * NN + dg;
      int pos = offs[r * NN + dg] + (int)bpfx[o] + (int)rank[base + i];
      esrc[pos] = src[base + i];
    }
  }
}

// ======== f32 -> bf16 cast ========
__global__ void k_cast(const float4* __restrict__ in, u16x4* __restrict__ out, int n4) {
  int i = blockIdx.x * 256 + threadIdx.x;
  if (i >= n4) return;
  float4 v = in[i];
  u16x4 o;
  o.x = f2b(v.x); o.y = f2b(v.y); o.z = f2b(v.z); o.w = f2b(v.w);
  out[i] = o;
}

// ======== Bel: [r][k][16] = [Wg.al (3) | Wg.ar (3) | 0 pad] ========
__global__ void k_wel(const float* __restrict__ Wg, const float* __restrict__ al,
                      const float* __restrict__ ar, float* __restrict__ Bel) {
  int i = blockIdx.x * 256 + threadIdx.x;
  if (i >= RR * HID * 16) return;  // 3072
  int col = i & 15;
  int k = (i >> 4) % HID;
  int r = i / (16 * HID);
  float v = 0.f;
  if (col < 6) {
    int isar = col / 3, h = col % 3;
    const float* wg = Wg + ((size_t)(r * HID + k)) * (NH * HID) + h * HID;
    const float* av = (isar ? ar : al) + (r * NH + h) * HID;
    float a = 0.f;
#pragma unroll 8
    for (int c = 0; c < HID; ++c) a += wg[c] * av[c];
    v = a;
  }
  Bel[i] = v;
}

// ======== stacked-K weight builders + bias sums ========
// Bg[h][r*64+k][o] = Wg[r][k][h*64+o]; B2s[r*64+k][o] = W2[r][k][o]
__global__ void k_wstack(const float* __restrict__ Wg, const float* __restrict__ W2,
                         const float* __restrict__ bg, const float* __restrict__ b2,
                         float* __restrict__ Bg, float* __restrict__ B2s,
                         float* __restrict__ bgs, float* __restrict__ b2s) {
  int i = blockIdx.x * 256 + threadIdx.x;
  const int NG = RR * 192 * 64;   // 36864
  const int N2 = 192 * 64;        // 12288
  if (i < NG) {
    int o = i & 63;
    int rk = (i >> 6) % 192;
    int h = i / (192 * 64);
    int r = rk >> 6, k = rk & 63;
    Bg[i] = Wg[((size_t)(r * HID + k)) * (NH * HID) + h * HID + o];
  } else if (i < NG + N2) {
    int j = i - NG;
    int o = j & 63;
    int rk = j >> 6;
    int r = rk >> 6, k = rk & 63;
    B2s[j] = W2[((size_t)(r * HID + k)) * FOUT + o];
  } else if (i < NG + N2 + 192) {
    int j = i - NG - N2;
    bgs[j] = bg[j] + bg[192 + j] + bg[384 + j];
  } else if (i < NG + N2 + 192 + 64) {
    int j = i - NG - N2 - 192;
    b2s[j] = b2[j] + b2[64 + j] + b2[128 + j];
  }
}

// ======== MFMA GEMM, 4 epilogue modes ========
// 1: conv1 -> u8 c1pk[(y*M+row)*64+col] = fp8(acc*scale[row]*QS)   (y = relation)
// 4: elr   -> N=16; cols 0..5 -> elr[(y*M+row)*8 + {0,1,2,4,5,6}] bf16 (y = rel)
// 5: gat-out  -> u8 gq[row*192 + y*64+col] = fp8(relu(acc*IQS+bias[y*64+col])*QS)
// 6: conv2-out-> u16 agg2b[row*192+y*64+col] = bf16(sigmoid(acc*IQS+bias[col]))
template <int K, int N, int OUTMODE>
__global__ __launch_bounds__(256) void k_gemm(const u16* __restrict__ A, int lda,
                                              const float* __restrict__ B0, int bstr,
                                              void* __restrict__ C0,
                                              const float* __restrict__ bias,
                                              const float* __restrict__ s0, int M) {
  constexpr int KP = K + 8;
  __shared__ __align__(16) u16 Bt[N * KP];
  int y = blockIdx.y;
  const float* B = B0 + (size_t)y * bstr;
  const u16* Ab = (OUTMODE == 5 || OUTMODE == 6) ? A + y * 192 : A;
  for (int i = threadIdx.x; i < K * N; i += 256) {
    int k = i / N, n = i % N;
    Bt[n * KP + k] = f2b(B[(size_t)k * N + n]);
  }
  __syncthreads();
  int wid = threadIdx.x >> 6, lane = threadIdx.x & 63;
  int l15 = lane & 15, lg = lane >> 4;
  constexpr int NT = N / 16;
  int ntiles = (M + 63) >> 6;
  for (int tile = blockIdx.x; tile < ntiles; tile += gridDim.x) {
    int mbase = tile * 64 + wid * 16;
    v4f acc[NT];
#pragma unroll
    for (int t = 0; t < NT; ++t) acc[t] = (v4f)(0.f);
    int arow = mbase + l15;
    if (arow >= M) arow = M - 1;
    const u16* ap = Ab + (size_t)arow * lda + lg * 8;
#pragma unroll
    for (int ks = 0; ks < K / 32; ++ks) {
      v8s a = *(const v8s*)(ap + ks * 32);
#pragma unroll
      for (int t = 0; t < NT; ++t) {
        v8s b = *(const v8s*)(&Bt[(t * 16 + l15) * KP + lg * 8 + ks * 32]);
        acc[t] = __builtin_amdgcn_mfma_f32_16x16x32_bf16(a, b, acc[t], 0, 0, 0);
      }
    }
#pragma unroll
    for (int q = 0; q < 4; ++q) {
      int row = mbase + lg * 4 + q;
      if (row >= M) continue;
      if (OUTMODE == 1) {
        float s = s0[(size_t)y * NN + row] * QS;
        u8* C = (u8*)C0 + ((size_t)y * M + row) * 64;
#pragma unroll
        for (int t = 0; t < NT; ++t) C[t * 16 + l15] = f2e(acc[t][q] * s);
      } else if (OUTMODE == 4) {
        if (l15 < 6)
          ((u16*)C0)[((size_t)y * M + row) * 8 + (l15 < 3 ? l15 : l15 + 1)] =
              f2b(acc[0][q]);
      } else if (OUTMODE == 5) {
        u8* C = (u8*)C0 + (size_t)row * 192 + y * 64;
#pragma unroll
        for (int t = 0; t < NT; ++t) {
          float v = acc[t][q] * IQS + bias[y * 64 + t * 16 + l15];
          C[t * 16 + l15] = f2e(fmaxf(v, 0.f) * QS);
        }
      } else {  // 6
        u16* C = (u16*)C0 + (size_t)row * 192 + y * 64;
#pragma unroll
        for (int t = 0; t < NT; ++t) {
          float v = acc[t][q] * IQS + bias[t * 16 + l15];
          C[t * 16 + l15] = f2b(1.0f / (1.0f + __expf(-v)));
        }
      }
    }
  }
}

// ======== conv1 gather (fp8, unroll 4) + bias + L2norm -> h1b (bf16) + h1q (fp8)
__global__ void k_g1(const int* __restrict__ offs, const int* __restrict__ degd,
                     const int* __restrict__ esrc, const u8* __restrict__ c1pk,
                     const float* __restrict__ nd, const float* __restrict__ b1,
                     u16* __restrict__ h1b, u8* __restrict__ h1q) {
  int node = blockIdx.x * 4 + (threadIdx.x >> 6);
  int lane = threadIdx.x & 63;
  if (node >= NN) return;
  float v = 0.f;
#pragma unroll
  for (int r = 0; r < RR; ++r) {
    int start = offs[r * NN + node];
    int deg = degd[r * NN + node];
    const u8* base = c1pk + (size_t)r * NN * 64 + lane;
    float t = 0.f;
    int j = 0;
    for (; j + 4 <= deg; j += 4) {
      int s0 = esrc[start + j], s1 = esrc[start + j + 1];
      int s2 = esrc[start + j + 2], s3 = esrc[start + j + 3];
      float a0 = __builtin_amdgcn_cvt_f32_fp8((u32)base[(size_t)s0 * 64], 0);
      float a1 = __builtin_amdgcn_cvt_f32_fp8((u32)base[(size_t)s1 * 64], 0);
      float a2 = __builtin_amdgcn_cvt_f32_fp8((u32)base[(size_t)s2 * 64], 0);
      float a3 = __builtin_amdgcn_cvt_f32_fp8((u32)base[(size_t)s3 * 64], 0);
      t += (a0 + a1) + (a2 + a3);
    }
    for (; j < deg; ++j)
      t += __builtin_amdgcn_cvt_f32_fp8((u32)base[(size_t)esrc[start + j] * 64], 0);
    v += t * nd[r * NN + node];
  }
  v = v * IQS + b1[lane] + b1[HID + lane] + b1[2 * HID + lane];
  float sq = v * v;
  for (int off = 32; off; off >>= 1) sq += __shfl_xor(sq, off);
  float nrm = sqrtf(sq);
  nrm = nrm > 1e-12f ? nrm : 1e-12f;
  float hv = v / nrm;
  h1b[node * HID + lane] = f2b(hv);
  h1q[node * HID + lane] = f2e(hv * QS);
}

// ======== normalized per-edge alphas (two passes per dst node) ========
__global__ void k_ew2(const int* __restrict__ offs, const int* __restrict__ degd,
                      const int* __restrict__ esrc, const u16* __restrict__ elr,
                      u16* __restrict__ ew) {
  int i = blockIdx.x * 256 + threadIdx.x;  // r*NN + node
  if (i >= RR * NN) return;
  int r = i / NN;
  int start = offs[i], deg = degd[i];
  const u16* ed = elr + (size_t)i * 8 + 4;  // er of dst
  float e0 = b2f(ed[0]), e1 = b2f(ed[1]), e2 = b2f(ed[2]);
  float z0 = 0.f, z1 = 0.f, z2 = 0.f;
  for (int j = 0; j < deg; ++j) {
    int s = esrc[start + j];
    const u16* es = elr + ((size_t)r * NN + s) * 8;
    z0 += wexp(b2f(es[0]) + e0);
    z1 += wexp(b2f(es[1]) + e1);
    z2 += wexp(b2f(es[2]) + e2);
  }
  float i0 = 1.f / (z0 + 1e-9f), i1 = 1.f / (z1 + 1e-9f), i2 = 1.f / (z2 + 1e-9f);
  for (int j = 0; j < deg; ++j) {
    int s = esrc[start + j];
    const u16* es = elr + ((size_t)r * NN + s) * 8;
    u16x4 o;
    o.x = f2b(wexp(b2f(es[0]) + e0) * i0);
    o.y = f2b(wexp(b2f(es[1]) + e1) * i1);
    o.z = f2b(wexp(b2f(es[2]) + e2) * i2);
    o.w = 0;
    *(u16x4*)(ew + (size_t)(start + j) * 4) = o;
  }
}

// ======== GAT gather on h1q (L2-resident 64-B rows) -> agg[n][h][r][64] bf16 ====
__global__ void k_gatg2(const int* __restrict__ offs, const int* __restrict__ degd,
                        const int* __restrict__ esrc, const u8* __restrict__ h1q,
                        const u16* __restrict__ ew, u16* __restrict__ agg) {
  int node = blockIdx.x * 4 + (threadIdx.x >> 6);
  int lane = threadIdx.x & 63;
  if (node >= NN) return;
  const u8* base = h1q + lane;
#pragma unroll
  for (int r = 0; r < RR; ++r) {
    int start = offs[r * NN + node];
    int deg = degd[r * NN + node];
    float a0 = 0.f, a1 = 0.f, a2 = 0.f;
    int j = 0;
    for (; j + 4 <= deg; j += 4) {
      int p = start + j;
      int s0 = esrc[p], s1 = esrc[p + 1], s2 = esrc[p + 2], s3 = esrc[p + 3];
      u16x4 wa = *(const u16x4*)(ew + (size_t)p * 4);
      u16x4 wb = *(const u16x4*)(ew + (size_t)(p + 1) * 4);
      u16x4 wc = *(const u16x4*)(ew + (size_t)(p + 2) * 4);
      u16x4 wd = *(const u16x4*)(ew + (size_t)(p + 3) * 4);
      float v0 = __builtin_amdgcn_cvt_f32_fp8((u32)base[(size_t)s0 * 64], 0);
      float v1 = __builtin_amdgcn_cvt_f32_fp8((u32)base[(size_t)s1 * 64], 0);
      float v2 = __builtin_amdgcn_cvt_f32_fp8((u32)base[(size_t)s2 * 64], 0);
      float v3 = __builtin_amdgcn_cvt_f32_fp8((u32)base[(size_t)s3 * 64], 0);
      a0 += b2f(wa.x) * v0 + b2f(wb.x) * v1 + b2f(wc.x) * v2 + b2f(wd.x) * v3;
      a1 += b2f(wa.y) * v0 + b2f(wb.y) * v1 + b2f(wc.y) * v2 + b2f(wd.y) * v3;
      a2 += b2f(wa.z) * v0 + b2f(wb.z) * v1 + b2f(wc.z) * v2 + b2f(wd.z) * v3;
    }
    for (; j < deg; ++j) {
      int p = start + j;
      u16x4 wa = *(const u16x4*)(ew + (size_t)p * 4);
      float v = __builtin_amdgcn_cvt_f32_fp8((u32)base[(size_t)esrc[p] * 64], 0);
      a0 += b2f(wa.x) * v;
      a1 += b2f(wa.y) * v;
      a2 += b2f(wa.z) * v;
    }
    size_t ob = (size_t)node * 576 + r * 64 + lane;
    agg[ob] = f2b(a0);
    agg[ob + 192] = f2b(a1);
    agg[ob + 384] = f2b(a2);
  }
}

// ======== conv2 gather on gq (fp8 relu feats) -> agg[n][h][r][64] bf16 ========
__global__ void k_g22(const int* __restrict__ offs, const int* __restrict__ degd,
                      const int* __restrict__ esrc, const u8* __restrict__ gq,
                      const float* __restrict__ ns, const float* __restrict__ nd,
                      u16* __restrict__ agg) {
  int node = blockIdx.x * 4 + (threadIdx.x >> 6);
  int lane = threadIdx.x & 63;
  if (node >= NN) return;
  const u8* g0 = gq + lane;
  const u8* g1 = gq + 64 + lane;
  const u8* g2 = gq + 128 + lane;
#pragma unroll
  for (int r = 0; r < RR; ++r) {
    int start = offs[r * NN + node];
    int deg = degd[r * NN + node];
    const float* nsr = ns + (size_t)r * NN;
    float a0 = 0.f, a1 = 0.f, a2 = 0.f;
    int j = 0;
    for (; j + 2 <= deg; j += 2) {
      int s0 = esrc[start + j], s1 = esrc[start + j + 1];
      float w0 = nsr[s0], w1 = nsr[s1];
      size_t o0 = (size_t)s0 * 192, o1 = (size_t)s1 * 192;
      a0 += w0 * __builtin_amdgcn_cvt_f32_fp8((u32)g0[o0], 0) +
            w1 * __builtin_amdgcn_cvt_f32_fp8((u32)g0[o1], 0);
      a1 += w0 * __builtin_amdgcn_cvt_f32_fp8((u32)g1[o0], 0) +
            w1 * __builtin_amdgcn_cvt_f32_fp8((u32)g1[o1], 0);
      a2 += w0 * __builtin_amdgcn_cvt_f32_fp8((u32)g2[o0], 0) +
            w1 * __builtin_amdgcn_cvt_f32_fp8((u32)g2[o1], 0);
    }
    if (j < deg) {
      int s0 = esrc[start + j];
      float w0 = nsr[s0];
      size_t o0 = (size_t)s0 * 192;
      a0 += w0 * __builtin_amdgcn_cvt_f32_fp8((u32)g0[o0], 0);
      a1 += w0 * __builtin_amdgcn_cvt_f32_fp8((u32)g1[o0], 0);
      a2 += w0 * __builtin_amdgcn_cvt_f32_fp8((u32)g2[o0], 0);
    }
    float ndv = nd[r * NN + node];
    size_t ob = (size_t)node * 576 + r * 64 + lane;
    agg[ob] = f2b(a0 * ndv);
    agg[ob + 192] = f2b(a1 * ndv);
    agg[ob + 384] = f2b(a2 * ndv);
  }
}

__global__ void k_cnt2(const int* __restrict__ gid, float* __restrict__ cnt) {
  __shared__ int loc[NB];
  if (threadIdx.x < NB) loc[threadIdx.x] = 0;
  __syncthreads();
  int i = blockIdx.x * 256 + threadIdx.x;
  if (i < NN) atomicAdd(&loc[gid[i]], 1);
  __syncthreads();
  if (threadIdx.x < NB) atomicAdd(&cnt[threadIdx.x], (float)loc[threadIdx.x]);
}

__global__ void k_pool(const u16* __restrict__ h3, const int* __restrict__ gid,
                       float* __restrict__ pooled) {
  int j = threadIdx.x;  // 0..191
  int start = blockIdx.x * 128;
  if (start >= NN) return;
  int end = start + 128;
  if (end > NN) end = NN;
  int gcur = gid[start];
  float acc = 0.f;
  for (int n = start; n < end; ++n) {
    int g = gid[n];
    if (g != gcur) {
      atomicAdd(&pooled[gcur * (NH * FOUT) + j], acc);
      acc = 0.f;
      gcur = g;
    }
    acc += b2f(h3[(size_t)n * (NH * FOUT) + j]);
  }
  atomicAdd(&pooled[gcur * (NH * FOUT) + j], acc);
}

__global__ void k_final(const float* __restrict__ pooled, const float* __restrict__ cnt,
                        const float* __restrict__ Wc, const float* __restrict__ bc,
                        float* __restrict__ out) {
  int t = threadIdx.x;
  if (t >= NB * NH) return;
  int b = t / NH;
  float inv = 1.0f / fmaxf(cnt[b], 1.0f);
  const float* p = pooled + t * FOUT;
  float sacc = 0.f;
  for (int c = 0; c < NC; ++c) {
    float acc = bc[c];
    for (int o = 0; o < FOUT; ++o) acc += p[o] * inv * Wc[o * NC + c];
    sacc += 1.0f / (1.0f + __expf(-acc));
  }
  out[t] = sacc * (1.0f / NC);
}

extern "C" void kernel_launch(void* const* d_in, const int* in_sizes, int n_in,
                              void* d_out, int out_size, void* d_ws, size_t ws_size,
                              hipStream_t stream) {
  const float* x = (const float*)d_in[0];
  const int* src = (const int*)d_in[1];
  const int* dst = (const int*)d_in[2];
  const int* gid = (const int*)d_in[3];
  const float* W1 = (const float*)d_in[4];
  const float* b1 = (const float*)d_in[5];
  const float* Wg = (const float*)d_in[6];
  const float* al = (const float*)d_in[7];
  const float* ar = (const float*)d_in[8];
  const float* bg = (const float*)d_in[9];
  const float* W2 = (const float*)d_in[10];
  const float* b2 = (const float*)d_in[11];
  const float* Wc = (const float*)d_in[12];
  const float* bc = (const float*)d_in[13];
  float* out = (float*)d_out;

  // ---- workspace layout (~119 MB; 144 MB proven in R2) ----
  float* cnt = (float*)d_ws;                      // 8
  float* pooled = cnt + NB;                       // 1536
  size_t zero_bytes = ((size_t)NB + NB * NH * FOUT) * 4;
  int* degd = (int*)(pooled + NB * NH * FOUT);    // 150000
  int* offs = degd + RR * NN;                     // 150000 (+8 pad)
  int* bsum = offs + RR * NN + 8;                 // 1024
  int* esrc = bsum + 1024;                        // 1200000
  float* ns = (float*)(esrc + (size_t)RR * EE);   // 150000
  float* nd = ns + RR * NN;                       // 150000
  float* Bel = nd + RR * NN;                      // 3072
  float* Bg = Bel + RR * HID * 16;                // 36864
  float* B2s = Bg + RR * 192 * 64;                // 12288
  float* bgs = B2s + 192 * 64;                    // 192
  float* b2s = bgs + 192;                         // 64
  u16* elr = (u16*)(b2s + 64);                    // RR*NN*8 u16 (2.4MB)
  u16* ew = elr + (size_t)RR * NN * 8;            // RR*EE*4 u16 (9.6MB)
  u16* xb = ew + (size_t)RR * EE * 4;             // NN*FIN u16 (12.8MB)
  u16* h1b = xb + (size_t)NN * FIN;               // NN*HID u16 (6.4MB)
  u8* h1q = (u8*)(h1b + (size_t)NN * HID);        // NN*64 u8 (3.2MB, L2-fit)
  u8* c1pk = h1q + (size_t)NN * HID;              // RR*NN*64 u8 (9.6MB)
  u8* gq = c1pk + (size_t)RR * NN * 64;           // NN*192 u8 (9.6MB)
  u16* agg = (u16*)(gq + (size_t)NN * 192);       // NN*576 u16 (57.6MB)
  u16* agg2b = xb;  // alias: xb+h1b (19.2MB) dead before conv2-out GEMM writes
  // CSR scratch aliases agg (dead before k_gatg2 writes agg): 31.2MB <= 57.6MB
  u16* ps = agg;                                  // RR*NBLK*NN u16 (9.6MB)
  u16* pd = ps + (size_t)RR * NBLK * NN;          // 9.6MB
  u16* bpfx = pd + (size_t)RR * NBLK * NN;        // 9.6MB
  u16* rank = bpfx + (size_t)RR * NBLK * NN;      // RR*EE u16 (2.4MB)

  hipMemsetAsync(d_ws, 0, zero_bytes, stream);

  const int nscan = RR * NN;
  const int nblk1 = (nscan + 255) / 256;

  // CSR build: LDS histograms -> reduce -> scan -> place (no global atomics)
  k_hist<<<dim3(NBLK, 8, RR), 1024, 0, stream>>>(src, dst, ps, pd, rank);
  k_red<<<nblk1, 256, 0, stream>>>(ps, pd, degd, ns, nd, bpfx);
  k_scan1<<<nblk1, 256, 0, stream>>>(degd, offs, bsum);
  k_scan2<<<1, 1024, 0, stream>>>(bsum, nblk1);
  k_scan3<<<nblk1, 256, 0, stream>>>(offs, bsum);
  k_place<<<dim3(NBLK, NRNG, RR), 1024, 0, stream>>>(src, dst, offs, bpfx, rank, esrc);

  // casts + weight prep
  k_cast<<<(NN * FIN / 4 + 255) / 256, 256, 0, stream>>>((const float4*)x, (u16x4*)xb,
                                                         NN * FIN / 4);
  k_wel<<<(RR * HID * 16 + 255) / 256, 256, 0, stream>>>(Wg, al, ar, Bel);
  k_wstack<<<(RR * 192 * 64 + 192 * 64 + 256 + 255) / 256, 256, 0, stream>>>(
      Wg, W2, bg, b2, Bg, B2s, bgs, b2s);

  // conv1: GEMM -> fp8 c1pk; gather+bias+L2norm -> h1b (bf16) + h1q (fp8)
  k_gemm<FIN, HID, 1><<<dim3(782, RR), 256, 0, stream>>>(
      xb, FIN, W1, FIN * HID, c1pk, nullptr, ns, NN);
  k_g1<<<(NN + 3) / 4, 256, 0, stream>>>(offs, degd, esrc, c1pk, nd, b1, h1b, h1q);

  // GAT: el/er via tiny GEMM; normalized alphas; h1q gather -> agg; out GEMM -> gq
  k_gemm<HID, 16, 4><<<dim3(782, RR), 256, 0, stream>>>(
      h1b, HID, Bel, HID * 16, elr, nullptr, nullptr, NN);
  k_ew2<<<nblk1, 256, 0, stream>>>(offs, degd, esrc, elr, ew);
  k_gatg2<<<(NN + 3) / 4, 256, 0, stream>>>(offs, degd, esrc, h1q, ew, agg);
  k_gemm<192, 64, 5><<<dim3(782, NH), 256, 0, stream>>>(
      agg, 576, Bg, 192 * 64, gq, bgs, nullptr, NN);

  // conv2: gq gather (ns fold, nd post) -> agg; out GEMM + sigmoid -> agg2b
  k_g22<<<(NN + 3) / 4, 256, 0, stream>>>(offs, degd, esrc, gq, ns, nd, agg);
  k_gemm<192, 64, 6><<<dim3(782, NH), 256, 0, stream>>>(
      agg, 576, B2s, 0, agg2b, b2s, nullptr, NN);

  // pooling + classifier
  k_cnt2<<<(NN + 255) / 256, 256, 0, stream>>>(gid, cnt);
  k_pool<<<(NN + 127) / 128, 192, 0, stream>>>(agg2b, gid, pooled);
  k_final<<<1, 64, 0, stream>>>(pooled, cnt, Wc, bc, out);
}